// Round 1
// baseline (472.902 us; speedup 1.0000x reference)
//
#include <hip/hip_runtime.h>
#include <stdint.h>

typedef __attribute__((ext_vector_type(8))) short short8;
typedef __attribute__((ext_vector_type(8))) __bf16 bf16x8;
typedef __attribute__((ext_vector_type(4))) float f32x4;

__device__ inline unsigned short f2bf(float f) {
  unsigned u = __float_as_uint(f);
  unsigned r = (u + 0x7FFFu + ((u >> 16) & 1u)) >> 16;  // RNE
  return (unsigned short)r;
}
__device__ inline float bflo(unsigned v) { return __uint_as_float(v << 16); }
__device__ inline float bfhi(unsigned v) { return __uint_as_float(v & 0xFFFF0000u); }
__device__ inline bf16x8 as_bf(short8 v) { return __builtin_bit_cast(bf16x8, v); }

// ---------------- prepass: convert X (f32) -> bf16, zero-pad rows >= n ----------------
__global__ void convert_x_kernel(const float* __restrict__ x, unsigned short* __restrict__ xb,
                                 int n, int mpad) {
  long i = (long)blockIdx.x * 256 + threadIdx.x;       // octet index
  long total = (long)mpad * 128;                       // mpad*1024/8
  if (i >= total) return;
  long e0 = i * 8;
  int row = (int)(e0 >> 10);
  short8 v;
  if (row < n) {
    const float* s = x + e0;
    float4 fa = *(const float4*)(s);
    float4 fb = *(const float4*)(s + 4);
    v[0] = (short)f2bf(fa.x); v[1] = (short)f2bf(fa.y);
    v[2] = (short)f2bf(fa.z); v[3] = (short)f2bf(fa.w);
    v[4] = (short)f2bf(fb.x); v[5] = (short)f2bf(fb.y);
    v[6] = (short)f2bf(fb.z); v[7] = (short)f2bf(fb.w);
  } else {
    v = (short8)0;
  }
  *(short8*)(xb + e0) = v;
}

// ---------------- prepass: W (f32, KxN row-major) -> Wt bf16 (NxK row-major) ----------------
__global__ void wtrans_kernel(const float* __restrict__ W, unsigned short* __restrict__ Wt) {
  __shared__ float tile[32][33];
  int bx = blockIdx.x & 31;   // n tile
  int by = blockIdx.x >> 5;   // k tile
  int tx = threadIdx.x & 31, ty = threadIdx.x >> 5;   // ty in 0..7
#pragma unroll
  for (int r = 0; r < 4; ++r) {
    int k = by * 32 + ty + r * 8;
    tile[ty + r * 8][tx] = W[(long)k * 1024 + bx * 32 + tx];
  }
  __syncthreads();
#pragma unroll
  for (int r = 0; r < 4; ++r) {
    int nrow = bx * 32 + ty + r * 8;
    int kcol = by * 32 + tx;
    Wt[(long)nrow * 1024 + kcol] = f2bf(tile[tx][ty + r * 8]);
  }
}

// ---------------- graph prep ----------------
__global__ void deg_kernel(const int* __restrict__ ei, int* __restrict__ degi, int E) {
  int e = blockIdx.x * 256 + threadIdx.x;
  if (e >= E) return;
  atomicAdd(&degi[ei[E + e]], 1);
}

__global__ void cnt_kernel(const int* __restrict__ batch, int* __restrict__ cnt, int N) {
  int i = blockIdx.x * 256 + threadIdx.x;
  if (i >= N) return;
  atomicAdd(&cnt[batch[i]], 1);
}

__global__ void dinv_kernel(const int* __restrict__ degi, float* __restrict__ dinv,
                            float* __restrict__ invd, int N) {
  int i = blockIdx.x * 256 + threadIdx.x;
  if (i >= N) return;
  float d = (float)(degi[i] + 1);
  dinv[i] = rsqrtf(d);
  invd[i] = 1.0f / d;
}

__global__ void scan_kernel(const int* __restrict__ deg, int* __restrict__ off,
                            int* __restrict__ cur, int n) {
  __shared__ int buf[1024];
  __shared__ int carry_s;
  int t = threadIdx.x;
  if (t == 0) carry_s = 0;
  __syncthreads();
  int nchunk = (n + 1023) / 1024;
  for (int c = 0; c < nchunk; ++c) {
    int i = c * 1024 + t;
    int v = (i < n) ? deg[i] : 0;
    buf[t] = v;
    __syncthreads();
    for (int s = 1; s < 1024; s <<= 1) {
      int x = (t >= s) ? buf[t - s] : 0;
      __syncthreads();
      buf[t] += x;
      __syncthreads();
    }
    int incl = buf[t];
    int base = carry_s;
    __syncthreads();
    if (i < n) { int ex = base + incl - v; off[i] = ex; cur[i] = ex; }
    if (t == 1023) carry_s = base + incl;
    __syncthreads();
  }
  if (t == 0) off[n] = carry_s;
}

__global__ void fill_kernel(const int* __restrict__ ei, int* __restrict__ cur,
                            int* __restrict__ csr, int E) {
  int e = blockIdx.x * 256 + threadIdx.x;
  if (e >= E) return;
  int s = ei[e], d = ei[E + e];
  int p = atomicAdd(&cur[d], 1);
  csr[p] = s;
}

// ---------------- GEMM: C[M,N] = A[M,K] @ Bt[N,K]^T  (bf16 in, bf16 out, f32 acc) ----------------
#define BM 128
#define BN 128
#define LDK 40   // padded LDS K-stride (bf16 elems)

__global__ __launch_bounds__(256) void gemm_bf16_kernel(
    const unsigned short* __restrict__ A, const unsigned short* __restrict__ Bt,
    unsigned short* __restrict__ C, int M, int Nn, int K) {
  __shared__ alignas(16) unsigned short As[BM * LDK];
  __shared__ alignas(16) unsigned short Bs[BN * LDK];
  int t = threadIdx.x;
  int lane = t & 63;
  int w = t >> 6;
  int wm = (w >> 1) * 64, wn = (w & 1) * 64;
  long m0 = (long)blockIdx.x * BM;
  long n0 = (long)blockIdx.y * BN;
  int sm = t >> 2;            // 0..63
  int sk = (t & 3) * 8;
  const unsigned short* Ab = A + m0 * K + sk;
  const unsigned short* Bb = Bt + n0 * K + sk;
  int fr = lane & 15;
  int fk = (lane >> 4) * 8;
  f32x4 acc[4][4] = {};
  for (int k0 = 0; k0 < K; k0 += 32) {
    short8 a0 = *(const short8*)(Ab + (long)sm * K + k0);
    short8 a1 = *(const short8*)(Ab + (long)(sm + 64) * K + k0);
    short8 b0 = *(const short8*)(Bb + (long)sm * K + k0);
    short8 b1 = *(const short8*)(Bb + (long)(sm + 64) * K + k0);
    __syncthreads();
    *(short8*)(As + sm * LDK + sk) = a0;
    *(short8*)(As + (sm + 64) * LDK + sk) = a1;
    *(short8*)(Bs + sm * LDK + sk) = b0;
    *(short8*)(Bs + (sm + 64) * LDK + sk) = b1;
    __syncthreads();
    short8 af[4], bf[4];
#pragma unroll
    for (int i = 0; i < 4; ++i)
      af[i] = *(const short8*)(As + (wm + i * 16 + fr) * LDK + fk);
#pragma unroll
    for (int i = 0; i < 4; ++i)
      bf[i] = *(const short8*)(Bs + (wn + i * 16 + fr) * LDK + fk);
#pragma unroll
    for (int i = 0; i < 4; ++i)
#pragma unroll
      for (int j = 0; j < 4; ++j)
        acc[i][j] = __builtin_amdgcn_mfma_f32_16x16x32_bf16(as_bf(af[i]), as_bf(bf[j]),
                                                            acc[i][j], 0, 0, 0);
  }
  int cr = (lane >> 4) * 4;
  int cc = lane & 15;
#pragma unroll
  for (int i = 0; i < 4; ++i)
#pragma unroll
    for (int j = 0; j < 4; ++j) {
      long row = m0 + wm + i * 16 + cr;
      long col = n0 + wn + j * 16 + cc;
      unsigned short* cp = C + row * Nn + col;
#pragma unroll
      for (int r = 0; r < 4; ++r)
        cp[(long)r * Nn] = f2bf(acc[i][j][r]);
    }
}

// ---------------- fused aggregate + bias + leaky + pool-accumulate ----------------
#define NPB 16
__global__ __launch_bounds__(256) void agg_pool_kernel(
    const unsigned short* __restrict__ H, const int* __restrict__ off,
    const int* __restrict__ csr, const float* __restrict__ dinv,
    const float* __restrict__ invd, const int* __restrict__ batch,
    const float* __restrict__ bias, float* __restrict__ pool, int n) {
  int t = threadIdx.x;
  int d0 = t * 4;
  int n0 = blockIdx.x * NPB;
  int nend = min(n0 + NPB, n);
  float bv[4];
#pragma unroll
  for (int j = 0; j < 4; ++j) bv[j] = bias[d0 + j];
  float pacc[4] = {0.f, 0.f, 0.f, 0.f};
  int curg = batch[n0];
  for (int nd = n0; nd < nend; ++nd) {
    int g = batch[nd];
    if (g != curg) {
#pragma unroll
      for (int j = 0; j < 4; ++j) atomicAdd(&pool[(long)curg * 1024 + d0 + j], pacc[j]);
#pragma unroll
      for (int j = 0; j < 4; ++j) pacc[j] = 0.f;
      curg = g;
    }
    float a0 = 0.f, a1 = 0.f, a2 = 0.f, a3 = 0.f;
    int eb = off[nd], ee = off[nd + 1];
    float dn = dinv[nd];
    int e = eb;
    for (; e + 2 <= ee; e += 2) {
      int s0 = csr[e], s1 = csr[e + 1];
      float w0 = dinv[s0] * dn, w1 = dinv[s1] * dn;
      uint2 h0 = *(const uint2*)(H + (long)s0 * 1024 + d0);
      uint2 h1 = *(const uint2*)(H + (long)s1 * 1024 + d0);
      a0 += w0 * bflo(h0.x) + w1 * bflo(h1.x);
      a1 += w0 * bfhi(h0.x) + w1 * bfhi(h1.x);
      a2 += w0 * bflo(h0.y) + w1 * bflo(h1.y);
      a3 += w0 * bfhi(h0.y) + w1 * bfhi(h1.y);
    }
    if (e < ee) {
      int s0 = csr[e];
      float w0 = dinv[s0] * dn;
      uint2 h0 = *(const uint2*)(H + (long)s0 * 1024 + d0);
      a0 += w0 * bflo(h0.x);
      a1 += w0 * bfhi(h0.x);
      a2 += w0 * bflo(h0.y);
      a3 += w0 * bfhi(h0.y);
    }
    float wi = invd[nd];
    uint2 hs = *(const uint2*)(H + (long)nd * 1024 + d0);
    a0 += wi * bflo(hs.x);
    a1 += wi * bfhi(hs.x);
    a2 += wi * bflo(hs.y);
    a3 += wi * bfhi(hs.y);
    float v0 = a0 + bv[0]; v0 = v0 >= 0.f ? v0 : 0.01f * v0;
    float v1 = a1 + bv[1]; v1 = v1 >= 0.f ? v1 : 0.01f * v1;
    float v2 = a2 + bv[2]; v2 = v2 >= 0.f ? v2 : 0.01f * v2;
    float v3 = a3 + bv[3]; v3 = v3 >= 0.f ? v3 : 0.01f * v3;
    pacc[0] += v0; pacc[1] += v1; pacc[2] += v2; pacc[3] += v3;
  }
#pragma unroll
  for (int j = 0; j < 4; ++j) atomicAdd(&pool[(long)curg * 1024 + d0 + j], pacc[j]);
}

// ---------------- final: mean-pool finalize + fc1/fc2 + leaky + concat @ final_W ----------------
__global__ __launch_bounds__(256) void fc_final_kernel(
    const float* __restrict__ pool1, const float* __restrict__ pool2,
    const int* __restrict__ cnt1, const int* __restrict__ cnt2,
    const float* __restrict__ fc1W, const float* __restrict__ fc1b,
    const float* __restrict__ fc2W, const float* __restrict__ fc2b,
    const float* __restrict__ finW, const float* __restrict__ finb,
    float* __restrict__ out) {
  __shared__ float p1[1024], p2[1024];
  __shared__ float red[256];
  int g = blockIdx.x, t = threadIdx.x;
  float ic1 = 1.0f / (float)max(cnt1[g], 1);
  float ic2 = 1.0f / (float)max(cnt2[g], 1);
  for (int i = t; i < 1024; i += 256) {
    p1[i] = pool1[(long)g * 1024 + i] * ic1;
    p2[i] = pool2[(long)g * 1024 + i] * ic2;
  }
  __syncthreads();
  float contrib;
  if (t < 128) {
    float a = 0.f;
    for (int k = 0; k < 1024; ++k) a += p1[k] * fc1W[(long)k * 128 + t];
    a += fc1b[t];
    a = a >= 0.f ? a : 0.01f * a;
    contrib = a * finW[t];
  } else {
    int j = t - 128;
    float a = 0.f;
    for (int k = 0; k < 1024; ++k) a += p2[k] * fc2W[(long)k * 128 + j];
    a += fc2b[j];
    a = a >= 0.f ? a : 0.01f * a;
    contrib = a * finW[128 + j];
  }
  red[t] = contrib;
  __syncthreads();
  for (int s = 128; s; s >>= 1) {
    if (t < s) red[t] += red[t + s];
    __syncthreads();
  }
  if (t == 0) out[g] = red[0] + finb[0];
}

extern "C" void kernel_launch(void* const* d_in, const int* in_sizes, int n_in,
                              void* d_out, int out_size, void* d_ws, size_t ws_size,
                              hipStream_t stream) {
  (void)n_in; (void)ws_size;
  const float* xs[2]   = {(const float*)d_in[0], (const float*)d_in[3]};
  const int* eis[2]    = {(const int*)d_in[1], (const int*)d_in[4]};
  const int* bts[2]    = {(const int*)d_in[2], (const int*)d_in[5]};
  const float* Ws[2]   = {(const float*)d_in[6], (const float*)d_in[10]};
  const float* bs[2]   = {(const float*)d_in[7], (const float*)d_in[11]};
  const float* fc1W = (const float*)d_in[8];
  const float* fc1b = (const float*)d_in[9];
  const float* fc2W = (const float*)d_in[12];
  const float* fc2b = (const float*)d_in[13];
  const float* finW = (const float*)d_in[14];
  const float* finb = (const float*)d_in[15];
  float* out = (float*)d_out;

  const int N = in_sizes[2];
  const int E = in_sizes[1] / 2;
  const int Mpad = ((N + 127) / 128) * 128;

  uint8_t* ws = (uint8_t*)d_ws;
  size_t o = 0;
  auto alloc = [&](size_t bytes) { size_t r = o; o += (bytes + 255) & ~(size_t)255; return r; };
  size_t degi_o[2] = {alloc((size_t)N * 4), alloc((size_t)N * 4)};
  size_t cnt_o[2]  = {alloc((size_t)out_size * 4), alloc((size_t)out_size * 4)};
  size_t pool_o[2] = {alloc((size_t)out_size * 1024 * 4), alloc((size_t)out_size * 1024 * 4)};
  size_t zero_end = o;
  size_t cur_o[2]  = {alloc((size_t)N * 4), alloc((size_t)N * 4)};
  size_t off_o[2]  = {alloc((size_t)(N + 1) * 4), alloc((size_t)(N + 1) * 4)};
  size_t csr_o[2]  = {alloc((size_t)E * 4), alloc((size_t)E * 4)};
  size_t dinv_o[2] = {alloc((size_t)N * 4), alloc((size_t)N * 4)};
  size_t invd_o[2] = {alloc((size_t)N * 4), alloc((size_t)N * 4)};
  size_t xb_o[2]   = {alloc((size_t)Mpad * 1024 * 2), alloc((size_t)Mpad * 1024 * 2)};
  size_t wt_o[2]   = {alloc((size_t)1024 * 1024 * 2), alloc((size_t)1024 * 1024 * 2)};
  size_t h_o[2]    = {alloc((size_t)Mpad * 1024 * 2), alloc((size_t)Mpad * 1024 * 2)};

  (void)hipMemsetAsync(ws, 0, zero_end, stream);

  for (int br = 0; br < 2; ++br) {
    convert_x_kernel<<<(int)(((long)Mpad * 128 + 255) / 256), 256, 0, stream>>>(
        xs[br], (unsigned short*)(ws + xb_o[br]), N, Mpad);
    wtrans_kernel<<<1024, 256, 0, stream>>>(Ws[br], (unsigned short*)(ws + wt_o[br]));
    deg_kernel<<<(E + 255) / 256, 256, 0, stream>>>(eis[br], (int*)(ws + degi_o[br]), E);
    cnt_kernel<<<(N + 255) / 256, 256, 0, stream>>>(bts[br], (int*)(ws + cnt_o[br]), N);
  }
  for (int br = 0; br < 2; ++br) {
    dinv_kernel<<<(N + 255) / 256, 256, 0, stream>>>(
        (int*)(ws + degi_o[br]), (float*)(ws + dinv_o[br]), (float*)(ws + invd_o[br]), N);
    scan_kernel<<<1, 1024, 0, stream>>>(
        (int*)(ws + degi_o[br]), (int*)(ws + off_o[br]), (int*)(ws + cur_o[br]), N);
    fill_kernel<<<(E + 255) / 256, 256, 0, stream>>>(
        eis[br], (int*)(ws + cur_o[br]), (int*)(ws + csr_o[br]), E);
  }
  for (int br = 0; br < 2; ++br) {
    dim3 grid(Mpad / BM, 1024 / BN);
    gemm_bf16_kernel<<<grid, 256, 0, stream>>>(
        (const unsigned short*)(ws + xb_o[br]), (const unsigned short*)(ws + wt_o[br]),
        (unsigned short*)(ws + h_o[br]), Mpad, 1024, 1024);
  }
  for (int br = 0; br < 2; ++br) {
    agg_pool_kernel<<<(N + NPB - 1) / NPB, 256, 0, stream>>>(
        (const unsigned short*)(ws + h_o[br]), (const int*)(ws + off_o[br]),
        (const int*)(ws + csr_o[br]), (const float*)(ws + dinv_o[br]),
        (const float*)(ws + invd_o[br]), bts[br], bs[br], (float*)(ws + pool_o[br]), N);
  }
  fc_final_kernel<<<out_size, 256, 0, stream>>>(
      (const float*)(ws + pool_o[0]), (const float*)(ws + pool_o[1]),
      (const int*)(ws + cnt_o[0]), (const int*)(ws + cnt_o[1]),
      fc1W, fc1b, fc2W, fc2b, finW, finb, out);
}

// Round 2
// 461.390 us; speedup vs baseline: 1.0250x; 1.0250x over previous
//
#include <hip/hip_runtime.h>
#include <stdint.h>

typedef __attribute__((ext_vector_type(8))) short short8;
typedef __attribute__((ext_vector_type(8))) __bf16 bf16x8;
typedef __attribute__((ext_vector_type(4))) float f32x4;

__device__ inline unsigned short f2bf(float f) {
  unsigned u = __float_as_uint(f);
  unsigned r = (u + 0x7FFFu + ((u >> 16) & 1u)) >> 16;  // RNE
  return (unsigned short)r;
}
__device__ inline float bflo(unsigned v) { return __uint_as_float(v << 16); }
__device__ inline float bfhi(unsigned v) { return __uint_as_float(v & 0xFFFF0000u); }
__device__ inline bf16x8 as_bf(short8 v) { return __builtin_bit_cast(bf16x8, v); }

#define GLOAD_LDS16(gp, lp)                                                   \
  __builtin_amdgcn_global_load_lds(                                           \
      (const __attribute__((address_space(1))) void*)(gp),                    \
      (__attribute__((address_space(3))) void*)(lp), 16, 0, 0)

// ---------------- prepass: convert X (f32) -> bf16, zero-pad rows >= n ----------------
__global__ void convert_x_kernel(const float* __restrict__ x, unsigned short* __restrict__ xb,
                                 int n, int mpad) {
  long i = (long)blockIdx.x * 256 + threadIdx.x;       // octet index
  long total = (long)mpad * 128;                       // mpad*1024/8
  if (i >= total) return;
  long e0 = i * 8;
  int row = (int)(e0 >> 10);
  short8 v;
  if (row < n) {
    const float* s = x + e0;
    float4 fa = *(const float4*)(s);
    float4 fb = *(const float4*)(s + 4);
    v[0] = (short)f2bf(fa.x); v[1] = (short)f2bf(fa.y);
    v[2] = (short)f2bf(fa.z); v[3] = (short)f2bf(fa.w);
    v[4] = (short)f2bf(fb.x); v[5] = (short)f2bf(fb.y);
    v[6] = (short)f2bf(fb.z); v[7] = (short)f2bf(fb.w);
  } else {
    v = (short8)0;
  }
  *(short8*)(xb + e0) = v;
}

// ---------------- prepass: W (f32, KxN row-major) -> Wt bf16 (NxK row-major) ----------------
__global__ void wtrans_kernel(const float* __restrict__ W, unsigned short* __restrict__ Wt) {
  __shared__ float tile[32][33];
  int bx = blockIdx.x & 31;   // n tile
  int by = blockIdx.x >> 5;   // k tile
  int tx = threadIdx.x & 31, ty = threadIdx.x >> 5;   // ty in 0..7
#pragma unroll
  for (int r = 0; r < 4; ++r) {
    int k = by * 32 + ty + r * 8;
    tile[ty + r * 8][tx] = W[(long)k * 1024 + bx * 32 + tx];
  }
  __syncthreads();
#pragma unroll
  for (int r = 0; r < 4; ++r) {
    int nrow = bx * 32 + ty + r * 8;
    int kcol = by * 32 + tx;
    Wt[(long)nrow * 1024 + kcol] = f2bf(tile[tx][ty + r * 8]);
  }
}

// ---------------- graph prep ----------------
__global__ void deg_kernel(const int* __restrict__ ei, int* __restrict__ degi, int E) {
  int e = blockIdx.x * 256 + threadIdx.x;
  if (e >= E) return;
  atomicAdd(&degi[ei[E + e]], 1);
}

__global__ void cnt_kernel(const int* __restrict__ batch, int* __restrict__ cnt, int N) {
  int i = blockIdx.x * 256 + threadIdx.x;
  if (i >= N) return;
  atomicAdd(&cnt[batch[i]], 1);
}

__global__ void dinv_kernel(const int* __restrict__ degi, float* __restrict__ dinv,
                            float* __restrict__ invd, int N) {
  int i = blockIdx.x * 256 + threadIdx.x;
  if (i >= N) return;
  float d = (float)(degi[i] + 1);
  dinv[i] = rsqrtf(d);
  invd[i] = 1.0f / d;
}

// one-pass scan for both branches (blockIdx.x = branch), 1024 threads
__global__ __launch_bounds__(1024) void scan2_kernel(
    const int* __restrict__ degA, int* __restrict__ offA, int* __restrict__ curA,
    const int* __restrict__ degB, int* __restrict__ offB, int* __restrict__ curB, int n) {
  const int* deg = blockIdx.x ? degB : degA;
  int* off = blockIdx.x ? offB : offA;
  int* cur = blockIdx.x ? curB : curA;
  __shared__ int wsum[17];
  int t = threadIdx.x, lane = t & 63, w = t >> 6;
  int CH = (n + 1023) >> 10;
  int i0 = t * CH;
  int s = 0;
  for (int i = 0; i < CH; ++i) {
    int idx = i0 + i;
    s += (idx < n) ? deg[idx] : 0;
  }
  int inc = s;
  for (int d = 1; d < 64; d <<= 1) {
    int x = __shfl_up(inc, d);
    if (lane >= d) inc += x;
  }
  if (lane == 63) wsum[w] = inc;
  __syncthreads();
  if (t == 0) {
    int r = 0;
    for (int k = 0; k < 16; ++k) { int x = wsum[k]; wsum[k] = r; r += x; }
    wsum[16] = r;
  }
  __syncthreads();
  int run = wsum[w] + inc - s;   // exclusive prefix of this thread's chunk
  for (int i = 0; i < CH; ++i) {
    int idx = i0 + i;
    if (idx < n) {
      off[idx] = run;
      cur[idx] = run;
      run += deg[idx];
    }
  }
  if (t == 0) off[n] = wsum[16];
}

__global__ void fill_kernel(const int* __restrict__ ei, int* __restrict__ cur,
                            int* __restrict__ csr, int E) {
  int e = blockIdx.x * 256 + threadIdx.x;
  if (e >= E) return;
  int s = ei[e], d = ei[E + e];
  int p = atomicAdd(&cur[d], 1);
  csr[p] = s;
}

// ---------------- GEMM: C[M,N] = A[M,K] @ Bt[N,K]^T (m97 structure: global_load_lds w16) ----------------
#define BM 128
#define BN 128
#define BK 32

__global__ __launch_bounds__(256) void gemm_bf16_kernel(
    const unsigned short* __restrict__ A, const unsigned short* __restrict__ Bt,
    unsigned short* __restrict__ C, int M, int Nn, int K) {
  __shared__ alignas(16) unsigned short As[BM * BK];
  __shared__ alignas(16) unsigned short Bs[BN * BK];
  int t = threadIdx.x;
  int lane = t & 63;
  int w = t >> 6;
  int wm = (w >> 1) * 64, wn = (w & 1) * 64;
  long m0 = (long)blockIdx.x * BM;
  long n0 = (long)blockIdx.y * BN;
  // staging: chunk c = t (+256 for round 1); row = c>>2 (0..63|64..127), col = (c&3)*8 elems
  int srow = t >> 2;
  int scol = (t & 3) * 8;
  const unsigned short* Ag = A + (m0 + srow) * K + scol;
  const unsigned short* Bg = Bt + (n0 + srow) * K + scol;
  unsigned short* AsP = As + t * 8;   // lane0-of-wave value = wave-uniform base
  unsigned short* BsP = Bs + t * 8;
  int fr = lane & 15;
  int fk = (lane >> 4) * 8;
  const unsigned short* afp = As + (wm + fr) * BK + fk;
  const unsigned short* bfp = Bs + (wn + fr) * BK + fk;
  f32x4 acc[4][4] = {};
  for (int k0 = 0; k0 < K; k0 += BK) {
    __syncthreads();   // previous iter's LDS reads done before overwrite
    GLOAD_LDS16(Ag + k0, AsP);
    GLOAD_LDS16(Ag + (long)64 * K + k0, AsP + 2048);
    GLOAD_LDS16(Bg + k0, BsP);
    GLOAD_LDS16(Bg + (long)64 * K + k0, BsP + 2048);
    __syncthreads();   // compiler drains vmcnt(0) before barrier
    short8 af[4], bf[4];
#pragma unroll
    for (int i = 0; i < 4; ++i)
      af[i] = *(const short8*)(afp + i * 16 * BK);
#pragma unroll
    for (int i = 0; i < 4; ++i)
      bf[i] = *(const short8*)(bfp + i * 16 * BK);
#pragma unroll
    for (int i = 0; i < 4; ++i)
#pragma unroll
      for (int j = 0; j < 4; ++j)
        acc[i][j] = __builtin_amdgcn_mfma_f32_16x16x32_bf16(as_bf(af[i]), as_bf(bf[j]),
                                                            acc[i][j], 0, 0, 0);
  }
  int cr = (lane >> 4) * 4;
  int cc = lane & 15;
#pragma unroll
  for (int i = 0; i < 4; ++i)
#pragma unroll
    for (int j = 0; j < 4; ++j) {
      long row = m0 + wm + i * 16 + cr;
      long col = n0 + wn + j * 16 + cc;
      unsigned short* cp = C + row * Nn + col;
#pragma unroll
      for (int r = 0; r < 4; ++r)
        cp[(long)r * Nn] = f2bf(acc[i][j][r]);
    }
}

// ---------------- fused aggregate + bias + leaky + pool-accumulate (XCD-sliced) ----------------
// slice = blockIdx.x % 8 -> XCD-private 128-dim column slice of H (2.5 MB, L2-resident)
#define NPB 32   // nodes per block; 8 groups x 4 nodes
__global__ __launch_bounds__(256) void agg_pool_kernel(
    const unsigned short* __restrict__ H, const int* __restrict__ off,
    const int* __restrict__ csr, const float* __restrict__ dinv,
    const float* __restrict__ invd, const int* __restrict__ batch,
    const float* __restrict__ bias, float* __restrict__ pool, int n) {
  int t = threadIdx.x;
  int grp = t >> 5;        // 0..7
  int l32 = t & 31;
  int slice = blockIdx.x & 7;
  int nb = blockIdx.x >> 3;
  int d0 = slice * 128 + l32 * 4;
  int n0 = nb * NPB + grp * (NPB / 8);
  if (n0 >= n) return;
  int nend = min(n0 + NPB / 8, n);
  float4 bv = *(const float4*)(bias + d0);
  float pacc[4] = {0.f, 0.f, 0.f, 0.f};
  int curg = batch[n0];
  for (int nd = n0; nd < nend; ++nd) {
    int g = batch[nd];
    if (g != curg) {
#pragma unroll
      for (int j = 0; j < 4; ++j) atomicAdd(&pool[(long)curg * 1024 + d0 + j], pacc[j]);
#pragma unroll
      for (int j = 0; j < 4; ++j) pacc[j] = 0.f;
      curg = g;
    }
    float a0 = 0.f, a1 = 0.f, a2 = 0.f, a3 = 0.f;
    int eb = off[nd], ee = off[nd + 1];
    float dn = dinv[nd];
    int e = eb;
    for (; e + 2 <= ee; e += 2) {
      int s0 = csr[e], s1 = csr[e + 1];
      float w0 = dinv[s0] * dn, w1 = dinv[s1] * dn;
      uint2 h0 = *(const uint2*)(H + (long)s0 * 1024 + d0);
      uint2 h1 = *(const uint2*)(H + (long)s1 * 1024 + d0);
      a0 += w0 * bflo(h0.x) + w1 * bflo(h1.x);
      a1 += w0 * bfhi(h0.x) + w1 * bfhi(h1.x);
      a2 += w0 * bflo(h0.y) + w1 * bflo(h1.y);
      a3 += w0 * bfhi(h0.y) + w1 * bfhi(h1.y);
    }
    if (e < ee) {
      int s0 = csr[e];
      float w0 = dinv[s0] * dn;
      uint2 h0 = *(const uint2*)(H + (long)s0 * 1024 + d0);
      a0 += w0 * bflo(h0.x);
      a1 += w0 * bfhi(h0.x);
      a2 += w0 * bflo(h0.y);
      a3 += w0 * bfhi(h0.y);
    }
    float wi = invd[nd];
    uint2 hs = *(const uint2*)(H + (long)nd * 1024 + d0);
    a0 += wi * bflo(hs.x);
    a1 += wi * bfhi(hs.x);
    a2 += wi * bflo(hs.y);
    a3 += wi * bfhi(hs.y);
    float v0 = a0 + bv.x; v0 = v0 >= 0.f ? v0 : 0.01f * v0;
    float v1 = a1 + bv.y; v1 = v1 >= 0.f ? v1 : 0.01f * v1;
    float v2 = a2 + bv.z; v2 = v2 >= 0.f ? v2 : 0.01f * v2;
    float v3 = a3 + bv.w; v3 = v3 >= 0.f ? v3 : 0.01f * v3;
    pacc[0] += v0; pacc[1] += v1; pacc[2] += v2; pacc[3] += v3;
  }
#pragma unroll
  for (int j = 0; j < 4; ++j) atomicAdd(&pool[(long)curg * 1024 + d0 + j], pacc[j]);
}

// ---------------- final: mean-pool finalize + fc1/fc2 + leaky + concat @ final_W ----------------
__global__ __launch_bounds__(256) void fc_final_kernel(
    const float* __restrict__ pool1, const float* __restrict__ pool2,
    const int* __restrict__ cnt1, const int* __restrict__ cnt2,
    const float* __restrict__ fc1W, const float* __restrict__ fc1b,
    const float* __restrict__ fc2W, const float* __restrict__ fc2b,
    const float* __restrict__ finW, const float* __restrict__ finb,
    float* __restrict__ out) {
  __shared__ float p1[1024], p2[1024];
  __shared__ float red[256];
  int g = blockIdx.x, t = threadIdx.x;
  float ic1 = 1.0f / (float)max(cnt1[g], 1);
  float ic2 = 1.0f / (float)max(cnt2[g], 1);
  for (int i = t; i < 1024; i += 256) {
    p1[i] = pool1[(long)g * 1024 + i] * ic1;
    p2[i] = pool2[(long)g * 1024 + i] * ic2;
  }
  __syncthreads();
  float contrib;
  if (t < 128) {
    float a = 0.f;
    for (int k = 0; k < 1024; ++k) a += p1[k] * fc1W[(long)k * 128 + t];
    a += fc1b[t];
    a = a >= 0.f ? a : 0.01f * a;
    contrib = a * finW[t];
  } else {
    int j = t - 128;
    float a = 0.f;
    for (int k = 0; k < 1024; ++k) a += p2[k] * fc2W[(long)k * 128 + j];
    a += fc2b[j];
    a = a >= 0.f ? a : 0.01f * a;
    contrib = a * finW[128 + j];
  }
  red[t] = contrib;
  __syncthreads();
  for (int s = 128; s; s >>= 1) {
    if (t < s) red[t] += red[t + s];
    __syncthreads();
  }
  if (t == 0) out[g] = red[0] + finb[0];
}

extern "C" void kernel_launch(void* const* d_in, const int* in_sizes, int n_in,
                              void* d_out, int out_size, void* d_ws, size_t ws_size,
                              hipStream_t stream) {
  (void)n_in; (void)ws_size;
  const float* xs[2]   = {(const float*)d_in[0], (const float*)d_in[3]};
  const int* eis[2]    = {(const int*)d_in[1], (const int*)d_in[4]};
  const int* bts[2]    = {(const int*)d_in[2], (const int*)d_in[5]};
  const float* Ws[2]   = {(const float*)d_in[6], (const float*)d_in[10]};
  const float* bs[2]   = {(const float*)d_in[7], (const float*)d_in[11]};
  const float* fc1W = (const float*)d_in[8];
  const float* fc1b = (const float*)d_in[9];
  const float* fc2W = (const float*)d_in[12];
  const float* fc2b = (const float*)d_in[13];
  const float* finW = (const float*)d_in[14];
  const float* finb = (const float*)d_in[15];
  float* out = (float*)d_out;

  const int N = in_sizes[2];
  const int E = in_sizes[1] / 2;
  const int Mpad = ((N + 127) / 128) * 128;

  uint8_t* ws = (uint8_t*)d_ws;
  size_t o = 0;
  auto alloc = [&](size_t bytes) { size_t r = o; o += (bytes + 255) & ~(size_t)255; return r; };
  size_t degi_o[2] = {alloc((size_t)N * 4), alloc((size_t)N * 4)};
  size_t cnt_o[2]  = {alloc((size_t)out_size * 4), alloc((size_t)out_size * 4)};
  size_t pool_o[2] = {alloc((size_t)out_size * 1024 * 4), alloc((size_t)out_size * 1024 * 4)};
  size_t zero_end = o;
  size_t cur_o[2]  = {alloc((size_t)N * 4), alloc((size_t)N * 4)};
  size_t off_o[2]  = {alloc((size_t)(N + 1) * 4), alloc((size_t)(N + 1) * 4)};
  size_t csr_o[2]  = {alloc((size_t)E * 4), alloc((size_t)E * 4)};
  size_t dinv_o[2] = {alloc((size_t)N * 4), alloc((size_t)N * 4)};
  size_t invd_o[2] = {alloc((size_t)N * 4), alloc((size_t)N * 4)};
  size_t xb_o[2]   = {alloc((size_t)Mpad * 1024 * 2), alloc((size_t)Mpad * 1024 * 2)};
  size_t wt_o[2]   = {alloc((size_t)1024 * 1024 * 2), alloc((size_t)1024 * 1024 * 2)};
  size_t h_o[2]    = {alloc((size_t)Mpad * 1024 * 2), alloc((size_t)Mpad * 1024 * 2)};

  (void)hipMemsetAsync(ws, 0, zero_end, stream);

  for (int br = 0; br < 2; ++br) {
    convert_x_kernel<<<(int)(((long)Mpad * 128 + 255) / 256), 256, 0, stream>>>(
        xs[br], (unsigned short*)(ws + xb_o[br]), N, Mpad);
    wtrans_kernel<<<1024, 256, 0, stream>>>(Ws[br], (unsigned short*)(ws + wt_o[br]));
    deg_kernel<<<(E + 255) / 256, 256, 0, stream>>>(eis[br], (int*)(ws + degi_o[br]), E);
    cnt_kernel<<<(N + 255) / 256, 256, 0, stream>>>(bts[br], (int*)(ws + cnt_o[br]), N);
  }
  for (int br = 0; br < 2; ++br) {
    dinv_kernel<<<(N + 255) / 256, 256, 0, stream>>>(
        (int*)(ws + degi_o[br]), (float*)(ws + dinv_o[br]), (float*)(ws + invd_o[br]), N);
  }
  scan2_kernel<<<2, 1024, 0, stream>>>(
      (const int*)(ws + degi_o[0]), (int*)(ws + off_o[0]), (int*)(ws + cur_o[0]),
      (const int*)(ws + degi_o[1]), (int*)(ws + off_o[1]), (int*)(ws + cur_o[1]), N);
  for (int br = 0; br < 2; ++br) {
    fill_kernel<<<(E + 255) / 256, 256, 0, stream>>>(
        eis[br], (int*)(ws + cur_o[br]), (int*)(ws + csr_o[br]), E);
  }
  for (int br = 0; br < 2; ++br) {
    dim3 grid(Mpad / BM, 1024 / BN);
    gemm_bf16_kernel<<<grid, 256, 0, stream>>>(
        (const unsigned short*)(ws + xb_o[br]), (const unsigned short*)(ws + wt_o[br]),
        (unsigned short*)(ws + h_o[br]), Mpad, 1024, 1024);
  }
  for (int br = 0; br < 2; ++br) {
    agg_pool_kernel<<<((N + NPB - 1) / NPB) * 8, 256, 0, stream>>>(
        (const unsigned short*)(ws + h_o[br]), (const int*)(ws + off_o[br]),
        (const int*)(ws + csr_o[br]), (const float*)(ws + dinv_o[br]),
        (const float*)(ws + invd_o[br]), bts[br], bs[br], (float*)(ws + pool_o[br]), N);
  }
  fc_final_kernel<<<out_size, 256, 0, stream>>>(
      (const float*)(ws + pool_o[0]), (const float*)(ws + pool_o[1]),
      (const int*)(ws + cnt_o[0]), (const int*)(ws + cnt_o[1]),
      fc1W, fc1b, fc2W, fc2b, finW, finb, out);
}

// Round 3
// 441.820 us; speedup vs baseline: 1.0704x; 1.0443x over previous
//
#include <hip/hip_runtime.h>
#include <stdint.h>

typedef __attribute__((ext_vector_type(8))) short short8;
typedef __attribute__((ext_vector_type(8))) __bf16 bf16x8;
typedef __attribute__((ext_vector_type(4))) float f32x4;

__device__ inline unsigned short f2bf(float f) {
  unsigned u = __float_as_uint(f);
  unsigned r = (u + 0x7FFFu + ((u >> 16) & 1u)) >> 16;  // RNE
  return (unsigned short)r;
}
__device__ inline float bflo(unsigned v) { return __uint_as_float(v << 16); }
__device__ inline float bfhi(unsigned v) { return __uint_as_float(v & 0xFFFF0000u); }
__device__ inline bf16x8 as_bf(short8 v) { return __builtin_bit_cast(bf16x8, v); }

#define GLOAD_LDS16(gp, lp)                                                   \
  __builtin_amdgcn_global_load_lds(                                           \
      (const __attribute__((address_space(1))) void*)(gp),                    \
      (__attribute__((address_space(3))) void*)(lp), 16, 0, 0)

// ---------------- prepass: convert X (f32) -> bf16, zero-pad rows >= n ----------------
__global__ void convert_x_kernel(const float* __restrict__ x, unsigned short* __restrict__ xb,
                                 int n, int mpad) {
  long i = (long)blockIdx.x * 256 + threadIdx.x;       // octet index
  long total = (long)mpad * 128;                       // mpad*1024/8
  if (i >= total) return;
  long e0 = i * 8;
  int row = (int)(e0 >> 10);
  short8 v;
  if (row < n) {
    const float* s = x + e0;
    float4 fa = *(const float4*)(s);
    float4 fb = *(const float4*)(s + 4);
    v[0] = (short)f2bf(fa.x); v[1] = (short)f2bf(fa.y);
    v[2] = (short)f2bf(fa.z); v[3] = (short)f2bf(fa.w);
    v[4] = (short)f2bf(fb.x); v[5] = (short)f2bf(fb.y);
    v[6] = (short)f2bf(fb.z); v[7] = (short)f2bf(fb.w);
  } else {
    v = (short8)0;
  }
  *(short8*)(xb + e0) = v;
}

// ---------------- prepass: W (f32, KxN row-major) -> Wt bf16 (NxK row-major) ----------------
__global__ void wtrans_kernel(const float* __restrict__ W, unsigned short* __restrict__ Wt) {
  __shared__ float tile[32][33];
  int bx = blockIdx.x & 31;   // n tile
  int by = blockIdx.x >> 5;   // k tile
  int tx = threadIdx.x & 31, ty = threadIdx.x >> 5;   // ty in 0..7
#pragma unroll
  for (int r = 0; r < 4; ++r) {
    int k = by * 32 + ty + r * 8;
    tile[ty + r * 8][tx] = W[(long)k * 1024 + bx * 32 + tx];
  }
  __syncthreads();
#pragma unroll
  for (int r = 0; r < 4; ++r) {
    int nrow = bx * 32 + ty + r * 8;
    int kcol = by * 32 + tx;
    Wt[(long)nrow * 1024 + kcol] = f2bf(tile[tx][ty + r * 8]);
  }
}

// ---------------- graph prep ----------------
__global__ void deg_kernel(const int* __restrict__ ei, int* __restrict__ degi, int E) {
  int e = blockIdx.x * 256 + threadIdx.x;
  if (e >= E) return;
  atomicAdd(&degi[ei[E + e]], 1);
}

__global__ void cnt_kernel(const int* __restrict__ batch, int* __restrict__ cnt, int N) {
  int i = blockIdx.x * 256 + threadIdx.x;
  if (i >= N) return;
  atomicAdd(&cnt[batch[i]], 1);
}

__global__ void dinv_kernel(const int* __restrict__ degi, float* __restrict__ dinv,
                            float* __restrict__ invd, int N) {
  int i = blockIdx.x * 256 + threadIdx.x;
  if (i >= N) return;
  float d = (float)(degi[i] + 1);
  dinv[i] = rsqrtf(d);
  invd[i] = 1.0f / d;
}

// one-pass scan for both branches (blockIdx.x = branch), 1024 threads
__global__ __launch_bounds__(1024) void scan2_kernel(
    const int* __restrict__ degA, int* __restrict__ offA, int* __restrict__ curA,
    const int* __restrict__ degB, int* __restrict__ offB, int* __restrict__ curB, int n) {
  const int* deg = blockIdx.x ? degB : degA;
  int* off = blockIdx.x ? offB : offA;
  int* cur = blockIdx.x ? curB : curA;
  __shared__ int wsum[17];
  int t = threadIdx.x, lane = t & 63, w = t >> 6;
  int CH = (n + 1023) >> 10;
  int i0 = t * CH;
  int s = 0;
  for (int i = 0; i < CH; ++i) {
    int idx = i0 + i;
    s += (idx < n) ? deg[idx] : 0;
  }
  int inc = s;
  for (int d = 1; d < 64; d <<= 1) {
    int x = __shfl_up(inc, d);
    if (lane >= d) inc += x;
  }
  if (lane == 63) wsum[w] = inc;
  __syncthreads();
  if (t == 0) {
    int r = 0;
    for (int k = 0; k < 16; ++k) { int x = wsum[k]; wsum[k] = r; r += x; }
    wsum[16] = r;
  }
  __syncthreads();
  int run = wsum[w] + inc - s;   // exclusive prefix of this thread's chunk
  for (int i = 0; i < CH; ++i) {
    int idx = i0 + i;
    if (idx < n) {
      off[idx] = run;
      cur[idx] = run;
      run += deg[idx];
    }
  }
  if (t == 0) off[n] = wsum[16];
}

// CSR fill, packing {src, edge_weight} into one uint2 per edge
__global__ void fill_kernel(const int* __restrict__ ei, const float* __restrict__ dinv,
                            int* __restrict__ cur, uint2* __restrict__ cw, int E) {
  int e = blockIdx.x * 256 + threadIdx.x;
  if (e >= E) return;
  int s = ei[e], d = ei[E + e];
  int p = atomicAdd(&cur[d], 1);
  uint2 v;
  v.x = (unsigned)s;
  v.y = __float_as_uint(dinv[s] * dinv[d]);
  cw[p] = v;
}

// edge-balanced node ranges: rng[q] = first node with off[node]*NG >= q*Etot
#define NG 2048
__global__ void ranges_kernel(const int* __restrict__ off, int* __restrict__ rng, int n) {
  int q = blockIdx.x * 256 + threadIdx.x;
  if (q > NG) return;
  if (q == NG) { rng[q] = n; return; }
  long Etot = off[n];
  long target = (long)q * Etot;
  int lo = 0, hi = n;
  while (lo < hi) {
    int mid = (lo + hi) >> 1;
    if ((long)off[mid] * NG >= target) hi = mid; else lo = mid + 1;
  }
  rng[q] = lo;
}

// ---------------- GEMM: C[M,N] = A[M,K] @ Bt[N,K]^T (m97 structure: global_load_lds w16) ----------------
#define BM 128
#define BN 128
#define BK 32

__global__ __launch_bounds__(256) void gemm_bf16_kernel(
    const unsigned short* __restrict__ A, const unsigned short* __restrict__ Bt,
    unsigned short* __restrict__ C, int M, int Nn, int K) {
  __shared__ alignas(16) unsigned short As[BM * BK];
  __shared__ alignas(16) unsigned short Bs[BN * BK];
  int t = threadIdx.x;
  int lane = t & 63;
  int w = t >> 6;
  int wm = (w >> 1) * 64, wn = (w & 1) * 64;
  long m0 = (long)blockIdx.x * BM;
  long n0 = (long)blockIdx.y * BN;
  int srow = t >> 2;
  int scol = (t & 3) * 8;
  const unsigned short* Ag = A + (m0 + srow) * K + scol;
  const unsigned short* Bg = Bt + (n0 + srow) * K + scol;
  unsigned short* AsP = As + t * 8;
  unsigned short* BsP = Bs + t * 8;
  int fr = lane & 15;
  int fk = (lane >> 4) * 8;
  const unsigned short* afp = As + (wm + fr) * BK + fk;
  const unsigned short* bfp = Bs + (wn + fr) * BK + fk;
  f32x4 acc[4][4] = {};
  for (int k0 = 0; k0 < K; k0 += BK) {
    __syncthreads();
    GLOAD_LDS16(Ag + k0, AsP);
    GLOAD_LDS16(Ag + (long)64 * K + k0, AsP + 2048);
    GLOAD_LDS16(Bg + k0, BsP);
    GLOAD_LDS16(Bg + (long)64 * K + k0, BsP + 2048);
    __syncthreads();
    short8 af[4], bf[4];
#pragma unroll
    for (int i = 0; i < 4; ++i)
      af[i] = *(const short8*)(afp + i * 16 * BK);
#pragma unroll
    for (int i = 0; i < 4; ++i)
      bf[i] = *(const short8*)(bfp + i * 16 * BK);
#pragma unroll
    for (int i = 0; i < 4; ++i)
#pragma unroll
      for (int j = 0; j < 4; ++j)
        acc[i][j] = __builtin_amdgcn_mfma_f32_16x16x32_bf16(as_bf(af[i]), as_bf(bf[j]),
                                                            acc[i][j], 0, 0, 0);
  }
  int cr = (lane >> 4) * 4;
  int cc = lane & 15;
#pragma unroll
  for (int i = 0; i < 4; ++i)
#pragma unroll
    for (int j = 0; j < 4; ++j) {
      long row = m0 + wm + i * 16 + cr;
      long col = n0 + wn + j * 16 + cc;
      unsigned short* cp = C + row * Nn + col;
#pragma unroll
      for (int r = 0; r < 4; ++r)
        cp[(long)r * Nn] = f2bf(acc[i][j][r]);
    }
}

// ---------------- fused aggregate + bias + leaky + pool-accumulate ----------------
// grid = 8 slices * 256 parts; 256 threads = 8 groups of 32 lanes.
// group q = part*8+grp handles nodes [rng[q], rng[q+1]) (edge-balanced),
// on dim slice [slice*128 + l32*4 .. +4). H slice is XCD-L2-resident.
__global__ __launch_bounds__(256) void agg_pool_kernel(
    const unsigned short* __restrict__ H, const int* __restrict__ off,
    const uint2* __restrict__ cw, const float* __restrict__ invd,
    const int* __restrict__ batch, const int* __restrict__ rng,
    const float* __restrict__ bias, float* __restrict__ pool, int n) {
  int t = threadIdx.x;
  int grp = t >> 5, l32 = t & 31;
  int slice = blockIdx.x & 7;
  int part = blockIdx.x >> 3;
  int q = part * 8 + grp;
  int d0 = slice * 128 + l32 * 4;
  int na = rng[q], nb = rng[q + 1];
  if (na < nb) {
    float4 bv = *(const float4*)(bias + d0);
    float pacc[4] = {0.f, 0.f, 0.f, 0.f};
    int curg = batch[na];
    for (int nd = na; nd < nb; ++nd) {
      int g = batch[nd];
      if (g != curg) {
#pragma unroll
        for (int j = 0; j < 4; ++j) atomicAdd(&pool[(long)curg * 1024 + d0 + j], pacc[j]);
#pragma unroll
        for (int j = 0; j < 4; ++j) pacc[j] = 0.f;
        curg = g;
      }
      float a0 = 0.f, a1 = 0.f, a2 = 0.f, a3 = 0.f;
      int eb = off[nd], ee = off[nd + 1];
      int e = eb;
      for (; e + 4 <= ee; e += 4) {
        uint2 c0 = cw[e], c1 = cw[e + 1], c2 = cw[e + 2], c3 = cw[e + 3];
        uint2 h0 = *(const uint2*)(H + (long)c0.x * 1024 + d0);
        uint2 h1 = *(const uint2*)(H + (long)c1.x * 1024 + d0);
        uint2 h2 = *(const uint2*)(H + (long)c2.x * 1024 + d0);
        uint2 h3 = *(const uint2*)(H + (long)c3.x * 1024 + d0);
        float w0 = __uint_as_float(c0.y), w1 = __uint_as_float(c1.y);
        float w2 = __uint_as_float(c2.y), w3 = __uint_as_float(c3.y);
        a0 += w0 * bflo(h0.x) + w1 * bflo(h1.x) + w2 * bflo(h2.x) + w3 * bflo(h3.x);
        a1 += w0 * bfhi(h0.x) + w1 * bfhi(h1.x) + w2 * bfhi(h2.x) + w3 * bfhi(h3.x);
        a2 += w0 * bflo(h0.y) + w1 * bflo(h1.y) + w2 * bflo(h2.y) + w3 * bflo(h3.y);
        a3 += w0 * bfhi(h0.y) + w1 * bfhi(h1.y) + w2 * bfhi(h2.y) + w3 * bfhi(h3.y);
      }
      for (; e < ee; ++e) {
        uint2 c0 = cw[e];
        uint2 h0 = *(const uint2*)(H + (long)c0.x * 1024 + d0);
        float w0 = __uint_as_float(c0.y);
        a0 += w0 * bflo(h0.x);
        a1 += w0 * bfhi(h0.x);
        a2 += w0 * bflo(h0.y);
        a3 += w0 * bfhi(h0.y);
      }
      float wi = invd[nd];
      uint2 hs = *(const uint2*)(H + (long)nd * 1024 + d0);
      a0 += wi * bflo(hs.x);
      a1 += wi * bfhi(hs.x);
      a2 += wi * bflo(hs.y);
      a3 += wi * bfhi(hs.y);
      float v0 = a0 + bv.x; v0 = v0 >= 0.f ? v0 : 0.01f * v0;
      float v1 = a1 + bv.y; v1 = v1 >= 0.f ? v1 : 0.01f * v1;
      float v2 = a2 + bv.z; v2 = v2 >= 0.f ? v2 : 0.01f * v2;
      float v3 = a3 + bv.w; v3 = v3 >= 0.f ? v3 : 0.01f * v3;
      pacc[0] += v0; pacc[1] += v1; pacc[2] += v2; pacc[3] += v3;
    }
#pragma unroll
    for (int j = 0; j < 4; ++j) atomicAdd(&pool[(long)curg * 1024 + d0 + j], pacc[j]);
  }
}

// ---------------- final: mean-pool finalize + fc1/fc2 + leaky + concat @ final_W ----------------
__global__ __launch_bounds__(256) void fc_final_kernel(
    const float* __restrict__ pool1, const float* __restrict__ pool2,
    const int* __restrict__ cnt1, const int* __restrict__ cnt2,
    const float* __restrict__ fc1W, const float* __restrict__ fc1b,
    const float* __restrict__ fc2W, const float* __restrict__ fc2b,
    const float* __restrict__ finW, const float* __restrict__ finb,
    float* __restrict__ out) {
  __shared__ float p1[1024], p2[1024];
  __shared__ float red[256];
  int g = blockIdx.x, t = threadIdx.x;
  float ic1 = 1.0f / (float)max(cnt1[g], 1);
  float ic2 = 1.0f / (float)max(cnt2[g], 1);
  for (int i = t; i < 1024; i += 256) {
    p1[i] = pool1[(long)g * 1024 + i] * ic1;
    p2[i] = pool2[(long)g * 1024 + i] * ic2;
  }
  __syncthreads();
  float contrib;
  if (t < 128) {
    float a = 0.f;
    for (int k = 0; k < 1024; ++k) a += p1[k] * fc1W[(long)k * 128 + t];
    a += fc1b[t];
    a = a >= 0.f ? a : 0.01f * a;
    contrib = a * finW[t];
  } else {
    int j = t - 128;
    float a = 0.f;
    for (int k = 0; k < 1024; ++k) a += p2[k] * fc2W[(long)k * 128 + j];
    a += fc2b[j];
    a = a >= 0.f ? a : 0.01f * a;
    contrib = a * finW[128 + j];
  }
  red[t] = contrib;
  __syncthreads();
  for (int s = 128; s; s >>= 1) {
    if (t < s) red[t] += red[t + s];
    __syncthreads();
  }
  if (t == 0) out[g] = red[0] + finb[0];
}

extern "C" void kernel_launch(void* const* d_in, const int* in_sizes, int n_in,
                              void* d_out, int out_size, void* d_ws, size_t ws_size,
                              hipStream_t stream) {
  (void)n_in; (void)ws_size;
  const float* xs[2]   = {(const float*)d_in[0], (const float*)d_in[3]};
  const int* eis[2]    = {(const int*)d_in[1], (const int*)d_in[4]};
  const int* bts[2]    = {(const int*)d_in[2], (const int*)d_in[5]};
  const float* Ws[2]   = {(const float*)d_in[6], (const float*)d_in[10]};
  const float* bs[2]   = {(const float*)d_in[7], (const float*)d_in[11]};
  const float* fc1W = (const float*)d_in[8];
  const float* fc1b = (const float*)d_in[9];
  const float* fc2W = (const float*)d_in[12];
  const float* fc2b = (const float*)d_in[13];
  const float* finW = (const float*)d_in[14];
  const float* finb = (const float*)d_in[15];
  float* out = (float*)d_out;

  const int N = in_sizes[2];
  const int E = in_sizes[1] / 2;
  const int Mpad = ((N + 127) / 128) * 128;

  uint8_t* ws = (uint8_t*)d_ws;
  size_t o = 0;
  auto alloc = [&](size_t bytes) { size_t r = o; o += (bytes + 255) & ~(size_t)255; return r; };
  size_t degi_o[2] = {alloc((size_t)N * 4), alloc((size_t)N * 4)};
  size_t cnt_o[2]  = {alloc((size_t)out_size * 4), alloc((size_t)out_size * 4)};
  size_t pool_o[2] = {alloc((size_t)out_size * 1024 * 4), alloc((size_t)out_size * 1024 * 4)};
  size_t zero_end = o;
  size_t cur_o[2]  = {alloc((size_t)N * 4), alloc((size_t)N * 4)};
  size_t off_o[2]  = {alloc((size_t)(N + 1) * 4), alloc((size_t)(N + 1) * 4)};
  size_t cw_o[2]   = {alloc((size_t)E * 8), alloc((size_t)E * 8)};
  size_t rng_o[2]  = {alloc((size_t)(NG + 1) * 4), alloc((size_t)(NG + 1) * 4)};
  size_t dinv_o[2] = {alloc((size_t)N * 4), alloc((size_t)N * 4)};
  size_t invd_o[2] = {alloc((size_t)N * 4), alloc((size_t)N * 4)};
  size_t xb_o[2]   = {alloc((size_t)Mpad * 1024 * 2), alloc((size_t)Mpad * 1024 * 2)};
  size_t wt_o[2]   = {alloc((size_t)1024 * 1024 * 2), alloc((size_t)1024 * 1024 * 2)};
  size_t h_o[2]    = {alloc((size_t)Mpad * 1024 * 2), alloc((size_t)Mpad * 1024 * 2)};

  (void)hipMemsetAsync(ws, 0, zero_end, stream);

  for (int br = 0; br < 2; ++br) {
    convert_x_kernel<<<(int)(((long)Mpad * 128 + 255) / 256), 256, 0, stream>>>(
        xs[br], (unsigned short*)(ws + xb_o[br]), N, Mpad);
    wtrans_kernel<<<1024, 256, 0, stream>>>(Ws[br], (unsigned short*)(ws + wt_o[br]));
    deg_kernel<<<(E + 255) / 256, 256, 0, stream>>>(eis[br], (int*)(ws + degi_o[br]), E);
    cnt_kernel<<<(N + 255) / 256, 256, 0, stream>>>(bts[br], (int*)(ws + cnt_o[br]), N);
  }
  for (int br = 0; br < 2; ++br) {
    dinv_kernel<<<(N + 255) / 256, 256, 0, stream>>>(
        (int*)(ws + degi_o[br]), (float*)(ws + dinv_o[br]), (float*)(ws + invd_o[br]), N);
  }
  scan2_kernel<<<2, 1024, 0, stream>>>(
      (const int*)(ws + degi_o[0]), (int*)(ws + off_o[0]), (int*)(ws + cur_o[0]),
      (const int*)(ws + degi_o[1]), (int*)(ws + off_o[1]), (int*)(ws + cur_o[1]), N);
  for (int br = 0; br < 2; ++br) {
    fill_kernel<<<(E + 255) / 256, 256, 0, stream>>>(
        eis[br], (const float*)(ws + dinv_o[br]), (int*)(ws + cur_o[br]),
        (uint2*)(ws + cw_o[br]), E);
    ranges_kernel<<<(NG + 256) / 256, 256, 0, stream>>>(
        (const int*)(ws + off_o[br]), (int*)(ws + rng_o[br]), N);
  }
  for (int br = 0; br < 2; ++br) {
    dim3 grid(Mpad / BM, 1024 / BN);
    gemm_bf16_kernel<<<grid, 256, 0, stream>>>(
        (const unsigned short*)(ws + xb_o[br]), (const unsigned short*)(ws + wt_o[br]),
        (unsigned short*)(ws + h_o[br]), Mpad, 1024, 1024);
  }
  for (int br = 0; br < 2; ++br) {
    agg_pool_kernel<<<256 * 8, 256, 0, stream>>>(
        (const unsigned short*)(ws + h_o[br]), (const int*)(ws + off_o[br]),
        (const uint2*)(ws + cw_o[br]), (const float*)(ws + invd_o[br]),
        bts[br], (const int*)(ws + rng_o[br]), bs[br], (float*)(ws + pool_o[br]), N);
  }
  fc_final_kernel<<<out_size, 256, 0, stream>>>(
      (const float*)(ws + pool_o[0]), (const float*)(ws + pool_o[1]),
      (const int*)(ws + cnt_o[0]), (const int*)(ws + cnt_o[1]),
      fc1W, fc1b, fc2W, fc2b, finW, finb, out);
}

// Round 4
// 435.419 us; speedup vs baseline: 1.0861x; 1.0147x over previous
//
#include <hip/hip_runtime.h>
#include <stdint.h>

typedef __attribute__((ext_vector_type(8))) short short8;
typedef __attribute__((ext_vector_type(8))) __bf16 bf16x8;
typedef __attribute__((ext_vector_type(4))) float f32x4;

__device__ inline unsigned short f2bf(float f) {
  unsigned u = __float_as_uint(f);
  unsigned r = (u + 0x7FFFu + ((u >> 16) & 1u)) >> 16;  // RNE
  return (unsigned short)r;
}
__device__ inline float bflo(unsigned v) { return __uint_as_float(v << 16); }
__device__ inline float bfhi(unsigned v) { return __uint_as_float(v & 0xFFFF0000u); }
__device__ inline bf16x8 as_bf(short8 v) { return __builtin_bit_cast(bf16x8, v); }

#define GLOAD_LDS16(gp, lp)                                                   \
  __builtin_amdgcn_global_load_lds(                                           \
      (const __attribute__((address_space(1))) void*)(gp),                    \
      (__attribute__((address_space(3))) void*)(lp), 16, 0, 0)

#define NG 2048   // edge-balanced node ranges
#define NSL 4     // dim slices (256 dims each)

// ---------------- prepass: convert X (f32) -> bf16, zero-pad rows >= n ----------------
__global__ void convert_x_kernel(const float* __restrict__ x, unsigned short* __restrict__ xb,
                                 int n, int mpad) {
  long i = (long)blockIdx.x * 256 + threadIdx.x;       // octet index
  long total = (long)mpad * 128;                       // mpad*1024/8
  if (i >= total) return;
  long e0 = i * 8;
  int row = (int)(e0 >> 10);
  short8 v;
  if (row < n) {
    const float* s = x + e0;
    float4 fa = *(const float4*)(s);
    float4 fb = *(const float4*)(s + 4);
    v[0] = (short)f2bf(fa.x); v[1] = (short)f2bf(fa.y);
    v[2] = (short)f2bf(fa.z); v[3] = (short)f2bf(fa.w);
    v[4] = (short)f2bf(fb.x); v[5] = (short)f2bf(fb.y);
    v[6] = (short)f2bf(fb.z); v[7] = (short)f2bf(fb.w);
  } else {
    v = (short8)0;
  }
  *(short8*)(xb + e0) = v;
}

// ---------------- prepass: W (f32, KxN row-major) -> Wt bf16 (NxK row-major) ----------------
__global__ void wtrans_kernel(const float* __restrict__ W, unsigned short* __restrict__ Wt) {
  __shared__ float tile[32][33];
  int bx = blockIdx.x & 31;   // n tile
  int by = blockIdx.x >> 5;   // k tile
  int tx = threadIdx.x & 31, ty = threadIdx.x >> 5;   // ty in 0..7
#pragma unroll
  for (int r = 0; r < 4; ++r) {
    int k = by * 32 + ty + r * 8;
    tile[ty + r * 8][tx] = W[(long)k * 1024 + bx * 32 + tx];
  }
  __syncthreads();
#pragma unroll
  for (int r = 0; r < 4; ++r) {
    int nrow = bx * 32 + ty + r * 8;
    int kcol = by * 32 + tx;
    Wt[(long)nrow * 1024 + kcol] = f2bf(tile[tx][ty + r * 8]);
  }
}

// ---------------- graph prep ----------------
__global__ void deg_kernel(const int* __restrict__ ei, int* __restrict__ degi, int E) {
  int e = blockIdx.x * 256 + threadIdx.x;
  if (e >= E) return;
  atomicAdd(&degi[ei[E + e]], 1);
}

__global__ void cnt_kernel(const int* __restrict__ batch, int* __restrict__ cnt, int N) {
  int i = blockIdx.x * 256 + threadIdx.x;
  if (i >= N) return;
  atomicAdd(&cnt[batch[i]], 1);
}

__global__ void dinv_kernel(const int* __restrict__ degi, float* __restrict__ dinv,
                            float* __restrict__ invd, int N) {
  int i = blockIdx.x * 256 + threadIdx.x;
  if (i >= N) return;
  float d = (float)(degi[i] + 1);
  dinv[i] = rsqrtf(d);
  invd[i] = 1.0f / d;
}

// one-pass scan over (deg+1) for both branches (blockIdx.x = branch); self-loop folded as edge
__global__ __launch_bounds__(1024) void scan2_kernel(
    const int* __restrict__ degA, int* __restrict__ offA, int* __restrict__ curA,
    const int* __restrict__ degB, int* __restrict__ offB, int* __restrict__ curB, int n) {
  const int* deg = blockIdx.x ? degB : degA;
  int* off = blockIdx.x ? offB : offA;
  int* cur = blockIdx.x ? curB : curA;
  __shared__ int wsum[17];
  int t = threadIdx.x, lane = t & 63, w = t >> 6;
  int CH = (n + 1023) >> 10;
  int i0 = t * CH;
  int s = 0;
  for (int i = 0; i < CH; ++i) {
    int idx = i0 + i;
    s += (idx < n) ? (deg[idx] + 1) : 0;
  }
  int inc = s;
  for (int d = 1; d < 64; d <<= 1) {
    int x = __shfl_up(inc, d);
    if (lane >= d) inc += x;
  }
  if (lane == 63) wsum[w] = inc;
  __syncthreads();
  if (t == 0) {
    int r = 0;
    for (int k = 0; k < 16; ++k) { int x = wsum[k]; wsum[k] = r; r += x; }
    wsum[16] = r;
  }
  __syncthreads();
  int run = wsum[w] + inc - s;
  for (int i = 0; i < CH; ++i) {
    int idx = i0 + i;
    if (idx < n) {
      off[idx] = run;
      cur[idx] = run;
      run += deg[idx] + 1;
    }
  }
  if (t == 0) off[n] = wsum[16];
}

// CSR fill with packed {src, weight}; e >= E are self-loops (weight 1/deg)
__global__ void fill_kernel(const int* __restrict__ ei, const float* __restrict__ dinv,
                            const float* __restrict__ invd, int* __restrict__ cur,
                            uint2* __restrict__ cw, int E, int N) {
  int e = blockIdx.x * 256 + threadIdx.x;
  if (e >= E + N) return;
  int s, d; float w;
  if (e < E) { s = ei[e]; d = ei[E + e]; w = dinv[s] * dinv[d]; }
  else { s = e - E; d = s; w = invd[s]; }
  int p = atomicAdd(&cur[d], 1);
  uint2 v; v.x = (unsigned)s; v.y = __float_as_uint(w);
  cw[p] = v;
}

// edge-balanced node ranges over off (includes self-edges)
__global__ void ranges_kernel(const int* __restrict__ off, int* __restrict__ rng, int n) {
  int q = blockIdx.x * 256 + threadIdx.x;
  if (q > NG) return;
  if (q == NG) { rng[q] = n; return; }
  long Etot = off[n];
  long target = (long)q * Etot;
  int lo = 0, hi = n;
  while (lo < hi) {
    int mid = (lo + hi) >> 1;
    if ((long)off[mid] * NG >= target) hi = mid; else lo = mid + 1;
  }
  rng[q] = lo;
}

// per-graph q-window: qrg[g] = {qlo, qhi, gs, ge}
__global__ void qrange_kernel(const int* __restrict__ cnt, const int* __restrict__ rng,
                              int4* __restrict__ qrg, int nb_) {
  int g = threadIdx.x;
  if (g >= nb_) return;
  int gs = 0;
  for (int i = 0; i < g; ++i) gs += cnt[i];
  int ge = gs + cnt[g];
  int lo = 0, hi = NG - 1;
  while (lo < hi) { int m = (lo + hi) >> 1; if (rng[m + 1] > gs) hi = m; else lo = m + 1; }
  int qlo = lo;
  lo = 0; hi = NG - 1;
  while (lo < hi) { int m = (lo + hi + 1) >> 1; if (rng[m] < ge) lo = m; else hi = m - 1; }
  int4 r; r.x = qlo; r.y = lo; r.z = gs; r.w = ge;
  qrg[g] = r;
}

// ---------------- GEMM: C[M,N] = A[M,K] @ Bt[N,K]^T (m97 structure: global_load_lds w16) ----------------
#define BM 128
#define BN 128
#define BK 32

__global__ __launch_bounds__(256) void gemm_bf16_kernel(
    const unsigned short* __restrict__ A, const unsigned short* __restrict__ Bt,
    unsigned short* __restrict__ C, int M, int Nn, int K) {
  __shared__ alignas(16) unsigned short As[BM * BK];
  __shared__ alignas(16) unsigned short Bs[BN * BK];
  int t = threadIdx.x;
  int lane = t & 63;
  int w = t >> 6;
  int wm = (w >> 1) * 64, wn = (w & 1) * 64;
  long m0 = (long)blockIdx.x * BM;
  long n0 = (long)blockIdx.y * BN;
  int srow = t >> 2;
  int scol = (t & 3) * 8;
  const unsigned short* Ag = A + (m0 + srow) * K + scol;
  const unsigned short* Bg = Bt + (n0 + srow) * K + scol;
  unsigned short* AsP = As + t * 8;
  unsigned short* BsP = Bs + t * 8;
  int fr = lane & 15;
  int fk = (lane >> 4) * 8;
  const unsigned short* afp = As + (wm + fr) * BK + fk;
  const unsigned short* bfp = Bs + (wn + fr) * BK + fk;
  f32x4 acc[4][4] = {};
  for (int k0 = 0; k0 < K; k0 += BK) {
    __syncthreads();
    GLOAD_LDS16(Ag + k0, AsP);
    GLOAD_LDS16(Ag + (long)64 * K + k0, AsP + 2048);
    GLOAD_LDS16(Bg + k0, BsP);
    GLOAD_LDS16(Bg + (long)64 * K + k0, BsP + 2048);
    __syncthreads();
    short8 af[4], bf[4];
#pragma unroll
    for (int i = 0; i < 4; ++i)
      af[i] = *(const short8*)(afp + i * 16 * BK);
#pragma unroll
    for (int i = 0; i < 4; ++i)
      bf[i] = *(const short8*)(bfp + i * 16 * BK);
#pragma unroll
    for (int i = 0; i < 4; ++i)
#pragma unroll
      for (int j = 0; j < 4; ++j)
        acc[i][j] = __builtin_amdgcn_mfma_f32_16x16x32_bf16(as_bf(af[i]), as_bf(bf[j]),
                                                            acc[i][j], 0, 0, 0);
  }
  int cr = (lane >> 4) * 4;
  int cc = lane & 15;
#pragma unroll
  for (int i = 0; i < 4; ++i)
#pragma unroll
    for (int j = 0; j < 4; ++j) {
      long row = m0 + wm + i * 16 + cr;
      long col = n0 + wn + j * 16 + cc;
      unsigned short* cp = C + row * Nn + col;
#pragma unroll
      for (int r = 0; r < 4; ++r)
        cp[(long)r * Nn] = f2bf(acc[i][j][r]);
    }
}

// ---------------- fused aggregate + bias + leaky + partial-pool (atomic-free) ----------------
// One 64-lane wave per (q, slice). Half-waves h=0/1 process edges e, e+1 of the SAME node
// (uniform control flow); lane covers 8 dims (16B uint4 loads). slices=4 (256 dims);
// blockIdx&3 = slice so each XCD touches exactly one 5MB H-slice.
// Per-range partials go non-atomically to scratch[q][slot 0|1][1024]; only graphs fully
// interior to a range (rare) use atomics. pool_reduce sums scratch afterwards.
__global__ __launch_bounds__(256) void agg_pool_kernel(
    const unsigned short* __restrict__ H, const int* __restrict__ off,
    const uint2* __restrict__ cw, const int* __restrict__ batch,
    const int* __restrict__ rng, const float* __restrict__ bias,
    float* __restrict__ pool, float* __restrict__ scratch, int* __restrict__ gid) {
  int t = threadIdx.x;
  int wv = t >> 6, lane = t & 63, h = lane >> 5, l32 = lane & 31;
  int slice = blockIdx.x & 3;
  int part = blockIdx.x >> 2;
  int q = part * 4 + wv;
  int d0 = slice * 256 + l32 * 8;
  int na = rng[q], nb = rng[q + 1];
  int g0 = -1, g1 = -1;
  if (na < nb) {
    float4 bv0 = *(const float4*)(bias + d0);
    float4 bv1 = *(const float4*)(bias + d0 + 4);
    float bv[8] = {bv0.x, bv0.y, bv0.z, bv0.w, bv1.x, bv1.y, bv1.z, bv1.w};
    float pacc[8] = {};
    int curg = batch[na];
    int fi = 0;
    for (int nd = na; nd < nb; ++nd) {
      int g = batch[nd];
      if (g != curg) {
        if (fi == 0) {
          g0 = curg;
          if (h == 0) {
            float* sp = scratch + ((long)q * 2 + 0) * 1024 + d0;
            *(float4*)sp = make_float4(pacc[0], pacc[1], pacc[2], pacc[3]);
            *(float4*)(sp + 4) = make_float4(pacc[4], pacc[5], pacc[6], pacc[7]);
          }
        } else {
          if (h == 0) {
            float* pp = pool + (long)curg * 1024 + d0;
#pragma unroll
            for (int k = 0; k < 8; ++k) atomicAdd(pp + k, pacc[k]);
          }
        }
        ++fi;
#pragma unroll
        for (int k = 0; k < 8; ++k) pacc[k] = 0.f;
        curg = g;
      }
      float a[8] = {};
      int eb = off[nd], ee = off[nd + 1];
      for (int e = eb; e < ee; e += 2) {
        int ei = e + h;
        int ec = ei < ee ? ei : ee - 1;
        uint2 c = cw[ec];
        float ww = ei < ee ? __uint_as_float(c.y) : 0.f;
        uint4 hv = *(const uint4*)(H + (long)c.x * 1024 + d0);
        a[0] += ww * bflo(hv.x); a[1] += ww * bfhi(hv.x);
        a[2] += ww * bflo(hv.y); a[3] += ww * bfhi(hv.y);
        a[4] += ww * bflo(hv.z); a[5] += ww * bfhi(hv.z);
        a[6] += ww * bflo(hv.w); a[7] += ww * bfhi(hv.w);
      }
#pragma unroll
      for (int k = 0; k < 8; ++k) {
        float v = a[k] + __shfl_xor(a[k], 32);
        v += bv[k];
        pacc[k] += (v >= 0.f) ? v : 0.01f * v;
      }
    }
    if (fi == 0) {
      g0 = curg;
      if (h == 0) {
        float* sp = scratch + ((long)q * 2 + 0) * 1024 + d0;
        *(float4*)sp = make_float4(pacc[0], pacc[1], pacc[2], pacc[3]);
        *(float4*)(sp + 4) = make_float4(pacc[4], pacc[5], pacc[6], pacc[7]);
      }
    } else {
      g1 = curg;
      if (h == 0) {
        float* sp = scratch + ((long)q * 2 + 1) * 1024 + d0;
        *(float4*)sp = make_float4(pacc[0], pacc[1], pacc[2], pacc[3]);
        *(float4*)(sp + 4) = make_float4(pacc[4], pacc[5], pacc[6], pacc[7]);
      }
    }
  }
  if (slice == 0 && lane == 0) {
    gid[q * 2] = g0;
    gid[q * 2 + 1] = g1;
  }
}

// sum scratch partials into pool (non-atomic; adds onto interior-atomic contributions)
__global__ __launch_bounds__(256) void pool_reduce_kernel(
    const float* __restrict__ scratch, const int* __restrict__ gid,
    const int4* __restrict__ qrg, float* __restrict__ pool) {
  int g = blockIdx.x >> 2;
  int slice = blockIdx.x & 3;
  int tid = threadIdx.x;
  int4 r = qrg[g];
  float s = 0.f;
  for (int q = r.x; q <= r.y; ++q) {
    int a = gid[q * 2], b = gid[q * 2 + 1];
    if (a == g) s += scratch[((long)q * 2 + 0) * 1024 + slice * 256 + tid];
    if (b == g) s += scratch[((long)q * 2 + 1) * 1024 + slice * 256 + tid];
  }
  long idx = (long)g * 1024 + slice * 256 + tid;
  pool[idx] += s;
}

// ---------------- final: mean-pool finalize + fc1/fc2 + leaky + concat @ final_W ----------------
__global__ __launch_bounds__(256) void fc_final_kernel(
    const float* __restrict__ pool1, const float* __restrict__ pool2,
    const int* __restrict__ cnt1, const int* __restrict__ cnt2,
    const float* __restrict__ fc1W, const float* __restrict__ fc1b,
    const float* __restrict__ fc2W, const float* __restrict__ fc2b,
    const float* __restrict__ finW, const float* __restrict__ finb,
    float* __restrict__ out) {
  __shared__ float p1[1024], p2[1024];
  __shared__ float red[256];
  int g = blockIdx.x, t = threadIdx.x;
  float ic1 = 1.0f / (float)max(cnt1[g], 1);
  float ic2 = 1.0f / (float)max(cnt2[g], 1);
  for (int i = t; i < 1024; i += 256) {
    p1[i] = pool1[(long)g * 1024 + i] * ic1;
    p2[i] = pool2[(long)g * 1024 + i] * ic2;
  }
  __syncthreads();
  float contrib;
  if (t < 128) {
    float a = 0.f;
    for (int k = 0; k < 1024; ++k) a += p1[k] * fc1W[(long)k * 128 + t];
    a += fc1b[t];
    a = a >= 0.f ? a : 0.01f * a;
    contrib = a * finW[t];
  } else {
    int j = t - 128;
    float a = 0.f;
    for (int k = 0; k < 1024; ++k) a += p2[k] * fc2W[(long)k * 128 + j];
    a += fc2b[j];
    a = a >= 0.f ? a : 0.01f * a;
    contrib = a * finW[128 + j];
  }
  red[t] = contrib;
  __syncthreads();
  for (int s = 128; s; s >>= 1) {
    if (t < s) red[t] += red[t + s];
    __syncthreads();
  }
  if (t == 0) out[g] = red[0] + finb[0];
}

extern "C" void kernel_launch(void* const* d_in, const int* in_sizes, int n_in,
                              void* d_out, int out_size, void* d_ws, size_t ws_size,
                              hipStream_t stream) {
  (void)n_in; (void)ws_size;
  const float* xs[2]   = {(const float*)d_in[0], (const float*)d_in[3]};
  const int* eis[2]    = {(const int*)d_in[1], (const int*)d_in[4]};
  const int* bts[2]    = {(const int*)d_in[2], (const int*)d_in[5]};
  const float* Ws[2]   = {(const float*)d_in[6], (const float*)d_in[10]};
  const float* bs[2]   = {(const float*)d_in[7], (const float*)d_in[11]};
  const float* fc1W = (const float*)d_in[8];
  const float* fc1b = (const float*)d_in[9];
  const float* fc2W = (const float*)d_in[12];
  const float* fc2b = (const float*)d_in[13];
  const float* finW = (const float*)d_in[14];
  const float* finb = (const float*)d_in[15];
  float* out = (float*)d_out;

  const int N = in_sizes[2];
  const int E = in_sizes[1] / 2;
  const int Mpad = ((N + 127) / 128) * 128;

  uint8_t* ws = (uint8_t*)d_ws;
  size_t o = 0;
  auto alloc = [&](size_t bytes) { size_t r = o; o += (bytes + 255) & ~(size_t)255; return r; };
  size_t degi_o[2] = {alloc((size_t)N * 4), alloc((size_t)N * 4)};
  size_t cnt_o[2]  = {alloc((size_t)out_size * 4), alloc((size_t)out_size * 4)};
  size_t pool_o[2] = {alloc((size_t)out_size * 1024 * 4), alloc((size_t)out_size * 1024 * 4)};
  size_t zero_end = o;
  size_t cur_o[2]  = {alloc((size_t)N * 4), alloc((size_t)N * 4)};
  size_t off_o[2]  = {alloc((size_t)(N + 1) * 4), alloc((size_t)(N + 1) * 4)};
  size_t cw_o[2]   = {alloc((size_t)(E + N) * 8), alloc((size_t)(E + N) * 8)};
  size_t rng_o[2]  = {alloc((size_t)(NG + 1) * 4), alloc((size_t)(NG + 1) * 4)};
  size_t dinv_o[2] = {alloc((size_t)N * 4), alloc((size_t)N * 4)};
  size_t invd_o[2] = {alloc((size_t)N * 4), alloc((size_t)N * 4)};
  size_t gid_o[2]  = {alloc((size_t)NG * 2 * 4), alloc((size_t)NG * 2 * 4)};
  size_t qrg_o[2]  = {alloc((size_t)out_size * 16), alloc((size_t)out_size * 16)};
  size_t scr_o[2]  = {alloc((size_t)NG * 2 * 1024 * 4), alloc((size_t)NG * 2 * 1024 * 4)};
  size_t xb_o[2]   = {alloc((size_t)Mpad * 1024 * 2), alloc((size_t)Mpad * 1024 * 2)};
  size_t wt_o[2]   = {alloc((size_t)1024 * 1024 * 2), alloc((size_t)1024 * 1024 * 2)};
  size_t h_o[2]    = {alloc((size_t)Mpad * 1024 * 2), alloc((size_t)Mpad * 1024 * 2)};

  (void)hipMemsetAsync(ws, 0, zero_end, stream);

  for (int br = 0; br < 2; ++br) {
    convert_x_kernel<<<(int)(((long)Mpad * 128 + 255) / 256), 256, 0, stream>>>(
        xs[br], (unsigned short*)(ws + xb_o[br]), N, Mpad);
    wtrans_kernel<<<1024, 256, 0, stream>>>(Ws[br], (unsigned short*)(ws + wt_o[br]));
    deg_kernel<<<(E + 255) / 256, 256, 0, stream>>>(eis[br], (int*)(ws + degi_o[br]), E);
    cnt_kernel<<<(N + 255) / 256, 256, 0, stream>>>(bts[br], (int*)(ws + cnt_o[br]), N);
  }
  for (int br = 0; br < 2; ++br) {
    dinv_kernel<<<(N + 255) / 256, 256, 0, stream>>>(
        (int*)(ws + degi_o[br]), (float*)(ws + dinv_o[br]), (float*)(ws + invd_o[br]), N);
  }
  scan2_kernel<<<2, 1024, 0, stream>>>(
      (const int*)(ws + degi_o[0]), (int*)(ws + off_o[0]), (int*)(ws + cur_o[0]),
      (const int*)(ws + degi_o[1]), (int*)(ws + off_o[1]), (int*)(ws + cur_o[1]), N);
  for (int br = 0; br < 2; ++br) {
    fill_kernel<<<(E + N + 255) / 256, 256, 0, stream>>>(
        eis[br], (const float*)(ws + dinv_o[br]), (const float*)(ws + invd_o[br]),
        (int*)(ws + cur_o[br]), (uint2*)(ws + cw_o[br]), E, N);
    ranges_kernel<<<(NG + 256) / 256, 256, 0, stream>>>(
        (const int*)(ws + off_o[br]), (int*)(ws + rng_o[br]), N);
  }
  for (int br = 0; br < 2; ++br) {
    qrange_kernel<<<1, 64, 0, stream>>>(
        (const int*)(ws + cnt_o[br]), (const int*)(ws + rng_o[br]),
        (int4*)(ws + qrg_o[br]), out_size);
  }
  for (int br = 0; br < 2; ++br) {
    dim3 grid(Mpad / BM, 1024 / BN);
    gemm_bf16_kernel<<<grid, 256, 0, stream>>>(
        (const unsigned short*)(ws + xb_o[br]), (const unsigned short*)(ws + wt_o[br]),
        (unsigned short*)(ws + h_o[br]), Mpad, 1024, 1024);
  }
  for (int br = 0; br < 2; ++br) {
    agg_pool_kernel<<<(NG / 4) * NSL, 256, 0, stream>>>(
        (const unsigned short*)(ws + h_o[br]), (const int*)(ws + off_o[br]),
        (const uint2*)(ws + cw_o[br]), bts[br], (const int*)(ws + rng_o[br]),
        bs[br], (float*)(ws + pool_o[br]), (float*)(ws + scr_o[br]), (int*)(ws + gid_o[br]));
  }
  for (int br = 0; br < 2; ++br) {
    pool_reduce_kernel<<<out_size * NSL, 256, 0, stream>>>(
        (const float*)(ws + scr_o[br]), (const int*)(ws + gid_o[br]),
        (const int4*)(ws + qrg_o[br]), (float*)(ws + pool_o[br]));
  }
  fc_final_kernel<<<out_size, 256, 0, stream>>>(
      (const float*)(ws + pool_o[0]), (const float*)(ws + pool_o[1]),
      (const int*)(ws + cnt_o[0]), (const int*)(ws + cnt_o[1]),
      fc1W, fc1b, fc2W, fc2b, finW, finb, out);
}

// Round 5
// 346.658 us; speedup vs baseline: 1.3642x; 1.2560x over previous
//
#include <hip/hip_runtime.h>
#include <stdint.h>

typedef __attribute__((ext_vector_type(8))) short short8;
typedef __attribute__((ext_vector_type(8))) __bf16 bf16x8;
typedef __attribute__((ext_vector_type(4))) float f32x4;

__device__ inline unsigned short f2bf(float f) {
  unsigned u = __float_as_uint(f);
  unsigned r = (u + 0x7FFFu + ((u >> 16) & 1u)) >> 16;  // RNE
  return (unsigned short)r;
}
__device__ inline float bflo(unsigned v) { return __uint_as_float(v << 16); }
__device__ inline float bfhi(unsigned v) { return __uint_as_float(v & 0xFFFF0000u); }
__device__ inline bf16x8 as_bf(short8 v) { return __builtin_bit_cast(bf16x8, v); }

#define GLOAD_LDS16(gp, lp)                                                   \
  __builtin_amdgcn_global_load_lds(                                           \
      (const __attribute__((address_space(1))) void*)(gp),                    \
      (__attribute__((address_space(3))) void*)(lp), 16, 0, 0)

#define NG 2048   // edge-balanced node ranges
#define NSL 4     // dim slices (256 dims each)

// ---------------- prepass: convert X (f32) -> bf16, zero-pad rows >= n ----------------
__global__ void convert_x_kernel(const float* __restrict__ x, unsigned short* __restrict__ xb,
                                 int n, int mpad) {
  long i = (long)blockIdx.x * 256 + threadIdx.x;       // octet index
  long total = (long)mpad * 128;                       // mpad*1024/8
  if (i >= total) return;
  long e0 = i * 8;
  int row = (int)(e0 >> 10);
  short8 v;
  if (row < n) {
    const float* s = x + e0;
    float4 fa = *(const float4*)(s);
    float4 fb = *(const float4*)(s + 4);
    v[0] = (short)f2bf(fa.x); v[1] = (short)f2bf(fa.y);
    v[2] = (short)f2bf(fa.z); v[3] = (short)f2bf(fa.w);
    v[4] = (short)f2bf(fb.x); v[5] = (short)f2bf(fb.y);
    v[6] = (short)f2bf(fb.z); v[7] = (short)f2bf(fb.w);
  } else {
    v = (short8)0;
  }
  *(short8*)(xb + e0) = v;
}

// ---------------- prepass: W (f32, KxN row-major) -> Wt bf16 (NxK row-major) ----------------
__global__ void wtrans_kernel(const float* __restrict__ W, unsigned short* __restrict__ Wt) {
  __shared__ float tile[32][33];
  int bx = blockIdx.x & 31;   // n tile
  int by = blockIdx.x >> 5;   // k tile
  int tx = threadIdx.x & 31, ty = threadIdx.x >> 5;   // ty in 0..7
#pragma unroll
  for (int r = 0; r < 4; ++r) {
    int k = by * 32 + ty + r * 8;
    tile[ty + r * 8][tx] = W[(long)k * 1024 + bx * 32 + tx];
  }
  __syncthreads();
#pragma unroll
  for (int r = 0; r < 4; ++r) {
    int nrow = bx * 32 + ty + r * 8;
    int kcol = by * 32 + tx;
    Wt[(long)nrow * 1024 + kcol] = f2bf(tile[tx][ty + r * 8]);
  }
}

// ---------------- graph prep ----------------
__global__ void deg_kernel(const int* __restrict__ ei, int* __restrict__ degi, int E) {
  int e = blockIdx.x * 256 + threadIdx.x;
  if (e >= E) return;
  atomicAdd(&degi[ei[E + e]], 1);
}

__global__ void dinv_kernel(const int* __restrict__ degi, float* __restrict__ dinv,
                            float* __restrict__ invd, int N) {
  int i = blockIdx.x * 256 + threadIdx.x;
  if (i >= N) return;
  float d = (float)(degi[i] + 1);
  dinv[i] = rsqrtf(d);
  invd[i] = 1.0f / d;
}

// one-pass scan over (deg+1) for both branches (blockIdx.x = branch); self-loop folded as edge
__global__ __launch_bounds__(1024) void scan2_kernel(
    const int* __restrict__ degA, int* __restrict__ offA, int* __restrict__ curA,
    const int* __restrict__ degB, int* __restrict__ offB, int* __restrict__ curB, int n) {
  const int* deg = blockIdx.x ? degB : degA;
  int* off = blockIdx.x ? offB : offA;
  int* cur = blockIdx.x ? curB : curA;
  __shared__ int wsum[17];
  int t = threadIdx.x, lane = t & 63, w = t >> 6;
  int CH = (n + 1023) >> 10;
  int i0 = t * CH;
  int s = 0;
  for (int i = 0; i < CH; ++i) {
    int idx = i0 + i;
    s += (idx < n) ? (deg[idx] + 1) : 0;
  }
  int inc = s;
  for (int d = 1; d < 64; d <<= 1) {
    int x = __shfl_up(inc, d);
    if (lane >= d) inc += x;
  }
  if (lane == 63) wsum[w] = inc;
  __syncthreads();
  if (t == 0) {
    int r = 0;
    for (int k = 0; k < 16; ++k) { int x = wsum[k]; wsum[k] = r; r += x; }
    wsum[16] = r;
  }
  __syncthreads();
  int run = wsum[w] + inc - s;
  for (int i = 0; i < CH; ++i) {
    int idx = i0 + i;
    if (idx < n) {
      off[idx] = run;
      cur[idx] = run;
      run += deg[idx] + 1;
    }
  }
  if (t == 0) off[n] = wsum[16];
}

// CSR fill with packed {src, weight}; e >= E are self-loops (weight 1/deg)
__global__ void fill_kernel(const int* __restrict__ ei, const float* __restrict__ dinv,
                            const float* __restrict__ invd, int* __restrict__ cur,
                            uint2* __restrict__ cw, int E, int N) {
  int e = blockIdx.x * 256 + threadIdx.x;
  if (e >= E + N) return;
  int s, d; float w;
  if (e < E) { s = ei[e]; d = ei[E + e]; w = dinv[s] * dinv[d]; }
  else { s = e - E; d = s; w = invd[s]; }
  int p = atomicAdd(&cur[d], 1);
  uint2 v; v.x = (unsigned)s; v.y = __float_as_uint(w);
  cw[p] = v;
}

// edge-balanced node ranges over off (includes self-edges)
__global__ void ranges_kernel(const int* __restrict__ off, int* __restrict__ rng, int n) {
  int q = blockIdx.x * 256 + threadIdx.x;
  if (q > NG) return;
  if (q == NG) { rng[q] = n; return; }
  long Etot = off[n];
  long target = (long)q * Etot;
  int lo = 0, hi = n;
  while (lo < hi) {
    int mid = (lo + hi) >> 1;
    if ((long)off[mid] * NG >= target) hi = mid; else lo = mid + 1;
  }
  rng[q] = lo;
}

// per-graph: node span via binary search on sorted batch (NO atomics), count, q-window
__global__ void qrange_kernel(const int* __restrict__ batch, int N,
                              const int* __restrict__ rng, int4* __restrict__ qrg,
                              int* __restrict__ cnt, int nb_) {
  int g = threadIdx.x;
  if (g >= nb_) return;
  int lo = 0, hi = N;
  while (lo < hi) { int m = (lo + hi) >> 1; if (batch[m] < g) lo = m + 1; else hi = m; }
  int gs = lo;
  lo = 0; hi = N;
  while (lo < hi) { int m = (lo + hi) >> 1; if (batch[m] <= g) lo = m + 1; else hi = m; }
  int ge = lo;
  cnt[g] = ge - gs;
  lo = 0; hi = NG - 1;
  while (lo < hi) { int m = (lo + hi) >> 1; if (rng[m + 1] > gs) hi = m; else lo = m + 1; }
  int qlo = lo;
  lo = 0; hi = NG - 1;
  while (lo < hi) { int m = (lo + hi + 1) >> 1; if (rng[m] < ge) lo = m; else hi = m - 1; }
  int4 r; r.x = qlo; r.y = lo; r.z = gs; r.w = ge;
  qrg[g] = r;
}

// ---------------- GEMM: C[M,N] = A[M,K] @ Bt[N,K]^T (m97 structure: global_load_lds w16) ----------------
#define BM 128
#define BN 128
#define BK 32

__global__ __launch_bounds__(256) void gemm_bf16_kernel(
    const unsigned short* __restrict__ A, const unsigned short* __restrict__ Bt,
    unsigned short* __restrict__ C, int M, int Nn, int K) {
  __shared__ alignas(16) unsigned short As[BM * BK];
  __shared__ alignas(16) unsigned short Bs[BN * BK];
  int t = threadIdx.x;
  int lane = t & 63;
  int w = t >> 6;
  int wm = (w >> 1) * 64, wn = (w & 1) * 64;
  long m0 = (long)blockIdx.x * BM;
  long n0 = (long)blockIdx.y * BN;
  int srow = t >> 2;
  int scol = (t & 3) * 8;
  const unsigned short* Ag = A + (m0 + srow) * K + scol;
  const unsigned short* Bg = Bt + (n0 + srow) * K + scol;
  unsigned short* AsP = As + t * 8;
  unsigned short* BsP = Bs + t * 8;
  int fr = lane & 15;
  int fk = (lane >> 4) * 8;
  const unsigned short* afp = As + (wm + fr) * BK + fk;
  const unsigned short* bfp = Bs + (wn + fr) * BK + fk;
  f32x4 acc[4][4] = {};
  for (int k0 = 0; k0 < K; k0 += BK) {
    __syncthreads();
    GLOAD_LDS16(Ag + k0, AsP);
    GLOAD_LDS16(Ag + (long)64 * K + k0, AsP + 2048);
    GLOAD_LDS16(Bg + k0, BsP);
    GLOAD_LDS16(Bg + (long)64 * K + k0, BsP + 2048);
    __syncthreads();
    short8 af[4], bf[4];
#pragma unroll
    for (int i = 0; i < 4; ++i)
      af[i] = *(const short8*)(afp + i * 16 * BK);
#pragma unroll
    for (int i = 0; i < 4; ++i)
      bf[i] = *(const short8*)(bfp + i * 16 * BK);
#pragma unroll
    for (int i = 0; i < 4; ++i)
#pragma unroll
      for (int j = 0; j < 4; ++j)
        acc[i][j] = __builtin_amdgcn_mfma_f32_16x16x32_bf16(as_bf(af[i]), as_bf(bf[j]),
                                                            acc[i][j], 0, 0, 0);
  }
  int cr = (lane >> 4) * 4;
  int cc = lane & 15;
#pragma unroll
  for (int i = 0; i < 4; ++i)
#pragma unroll
    for (int j = 0; j < 4; ++j) {
      long row = m0 + wm + i * 16 + cr;
      long col = n0 + wn + j * 16 + cc;
      unsigned short* cp = C + row * Nn + col;
#pragma unroll
      for (int r = 0; r < 4; ++r)
        cp[(long)r * Nn] = f2bf(acc[i][j][r]);
    }
}

// ---------------- fused aggregate + bias + leaky + partial-pool (atomic-free) ----------------
// One 64-lane wave per (q, slice). Half-waves h=0/1 process edges e, e+1 of the SAME node
// (uniform control flow); lane covers 8 dims (16B uint4 loads). slices=4 (256 dims);
// blockIdx&3 = slice so each XCD touches exactly one 5MB H-slice.
// Per-range partials go non-atomically to scratch[q][slot 0|1][1024]; only graphs fully
// interior to a range (rare) use atomics. pool_reduce sums scratch afterwards.
__global__ __launch_bounds__(256) void agg_pool_kernel(
    const unsigned short* __restrict__ H, const int* __restrict__ off,
    const uint2* __restrict__ cw, const int* __restrict__ batch,
    const int* __restrict__ rng, const float* __restrict__ bias,
    float* __restrict__ pool, float* __restrict__ scratch, int* __restrict__ gid) {
  int t = threadIdx.x;
  int wv = t >> 6, lane = t & 63, h = lane >> 5, l32 = lane & 31;
  int slice = blockIdx.x & 3;
  int part = blockIdx.x >> 2;
  int q = part * 4 + wv;
  int d0 = slice * 256 + l32 * 8;
  int na = rng[q], nb = rng[q + 1];
  int g0 = -1, g1 = -1;
  if (na < nb) {
    float4 bv0 = *(const float4*)(bias + d0);
    float4 bv1 = *(const float4*)(bias + d0 + 4);
    float bv[8] = {bv0.x, bv0.y, bv0.z, bv0.w, bv1.x, bv1.y, bv1.z, bv1.w};
    float pacc[8] = {};
    int curg = batch[na];
    int fi = 0;
    for (int nd = na; nd < nb; ++nd) {
      int g = batch[nd];
      if (g != curg) {
        if (fi == 0) {
          g0 = curg;
          if (h == 0) {
            float* sp = scratch + ((long)q * 2 + 0) * 1024 + d0;
            *(float4*)sp = make_float4(pacc[0], pacc[1], pacc[2], pacc[3]);
            *(float4*)(sp + 4) = make_float4(pacc[4], pacc[5], pacc[6], pacc[7]);
          }
        } else {
          if (h == 0) {
            float* pp = pool + (long)curg * 1024 + d0;
#pragma unroll
            for (int k = 0; k < 8; ++k) atomicAdd(pp + k, pacc[k]);
          }
        }
        ++fi;
#pragma unroll
        for (int k = 0; k < 8; ++k) pacc[k] = 0.f;
        curg = g;
      }
      float a[8] = {};
      int eb = off[nd], ee = off[nd + 1];
      for (int e = eb; e < ee; e += 2) {
        int ei = e + h;
        int ec = ei < ee ? ei : ee - 1;
        uint2 c = cw[ec];
        float ww = ei < ee ? __uint_as_float(c.y) : 0.f;
        uint4 hv = *(const uint4*)(H + (long)c.x * 1024 + d0);
        a[0] += ww * bflo(hv.x); a[1] += ww * bfhi(hv.x);
        a[2] += ww * bflo(hv.y); a[3] += ww * bfhi(hv.y);
        a[4] += ww * bflo(hv.z); a[5] += ww * bfhi(hv.z);
        a[6] += ww * bflo(hv.w); a[7] += ww * bfhi(hv.w);
      }
#pragma unroll
      for (int k = 0; k < 8; ++k) {
        float v = a[k] + __shfl_xor(a[k], 32);
        v += bv[k];
        pacc[k] += (v >= 0.f) ? v : 0.01f * v;
      }
    }
    if (fi == 0) {
      g0 = curg;
      if (h == 0) {
        float* sp = scratch + ((long)q * 2 + 0) * 1024 + d0;
        *(float4*)sp = make_float4(pacc[0], pacc[1], pacc[2], pacc[3]);
        *(float4*)(sp + 4) = make_float4(pacc[4], pacc[5], pacc[6], pacc[7]);
      }
    } else {
      g1 = curg;
      if (h == 0) {
        float* sp = scratch + ((long)q * 2 + 1) * 1024 + d0;
        *(float4*)sp = make_float4(pacc[0], pacc[1], pacc[2], pacc[3]);
        *(float4*)(sp + 4) = make_float4(pacc[4], pacc[5], pacc[6], pacc[7]);
      }
    }
  }
  if (slice == 0 && lane == 0) {
    gid[q * 2] = g0;
    gid[q * 2 + 1] = g1;
  }
}

// sum scratch partials into pool (non-atomic; adds onto interior-atomic contributions)
__global__ __launch_bounds__(256) void pool_reduce_kernel(
    const float* __restrict__ scratch, const int* __restrict__ gid,
    const int4* __restrict__ qrg, float* __restrict__ pool) {
  int g = blockIdx.x >> 2;
  int slice = blockIdx.x & 3;
  int tid = threadIdx.x;
  int4 r = qrg[g];
  float s = 0.f;
  for (int q = r.x; q <= r.y; ++q) {
    int a = gid[q * 2], b = gid[q * 2 + 1];
    if (a == g) s += scratch[((long)q * 2 + 0) * 1024 + slice * 256 + tid];
    if (b == g) s += scratch[((long)q * 2 + 1) * 1024 + slice * 256 + tid];
  }
  long idx = (long)g * 1024 + slice * 256 + tid;
  pool[idx] += s;
}

// ---------------- final: mean-pool finalize + fc1/fc2 + leaky + concat @ final_W ----------------
__global__ __launch_bounds__(256) void fc_final_kernel(
    const float* __restrict__ pool1, const float* __restrict__ pool2,
    const int* __restrict__ cnt1, const int* __restrict__ cnt2,
    const float* __restrict__ fc1W, const float* __restrict__ fc1b,
    const float* __restrict__ fc2W, const float* __restrict__ fc2b,
    const float* __restrict__ finW, const float* __restrict__ finb,
    float* __restrict__ out) {
  __shared__ float p1[1024], p2[1024];
  __shared__ float red[256];
  int g = blockIdx.x, t = threadIdx.x;
  float ic1 = 1.0f / (float)max(cnt1[g], 1);
  float ic2 = 1.0f / (float)max(cnt2[g], 1);
  for (int i = t; i < 1024; i += 256) {
    p1[i] = pool1[(long)g * 1024 + i] * ic1;
    p2[i] = pool2[(long)g * 1024 + i] * ic2;
  }
  __syncthreads();
  float contrib;
  if (t < 128) {
    float a = 0.f;
    for (int k = 0; k < 1024; ++k) a += p1[k] * fc1W[(long)k * 128 + t];
    a += fc1b[t];
    a = a >= 0.f ? a : 0.01f * a;
    contrib = a * finW[t];
  } else {
    int j = t - 128;
    float a = 0.f;
    for (int k = 0; k < 1024; ++k) a += p2[k] * fc2W[(long)k * 128 + j];
    a += fc2b[j];
    a = a >= 0.f ? a : 0.01f * a;
    contrib = a * finW[128 + j];
  }
  red[t] = contrib;
  __syncthreads();
  for (int s = 128; s; s >>= 1) {
    if (t < s) red[t] += red[t + s];
    __syncthreads();
  }
  if (t == 0) out[g] = red[0] + finb[0];
}

extern "C" void kernel_launch(void* const* d_in, const int* in_sizes, int n_in,
                              void* d_out, int out_size, void* d_ws, size_t ws_size,
                              hipStream_t stream) {
  (void)n_in; (void)ws_size;
  const float* xs[2]   = {(const float*)d_in[0], (const float*)d_in[3]};
  const int* eis[2]    = {(const int*)d_in[1], (const int*)d_in[4]};
  const int* bts[2]    = {(const int*)d_in[2], (const int*)d_in[5]};
  const float* Ws[2]   = {(const float*)d_in[6], (const float*)d_in[10]};
  const float* bs[2]   = {(const float*)d_in[7], (const float*)d_in[11]};
  const float* fc1W = (const float*)d_in[8];
  const float* fc1b = (const float*)d_in[9];
  const float* fc2W = (const float*)d_in[12];
  const float* fc2b = (const float*)d_in[13];
  const float* finW = (const float*)d_in[14];
  const float* finb = (const float*)d_in[15];
  float* out = (float*)d_out;

  const int N = in_sizes[2];
  const int E = in_sizes[1] / 2;
  const int Mpad = ((N + 127) / 128) * 128;

  uint8_t* ws = (uint8_t*)d_ws;
  size_t o = 0;
  auto alloc = [&](size_t bytes) { size_t r = o; o += (bytes + 255) & ~(size_t)255; return r; };
  size_t degi_o[2] = {alloc((size_t)N * 4), alloc((size_t)N * 4)};
  size_t pool_o[2] = {alloc((size_t)out_size * 1024 * 4), alloc((size_t)out_size * 1024 * 4)};
  size_t zero_end = o;
  size_t cnt_o[2]  = {alloc((size_t)out_size * 4), alloc((size_t)out_size * 4)};
  size_t cur_o[2]  = {alloc((size_t)N * 4), alloc((size_t)N * 4)};
  size_t off_o[2]  = {alloc((size_t)(N + 1) * 4), alloc((size_t)(N + 1) * 4)};
  size_t cw_o[2]   = {alloc((size_t)(E + N) * 8), alloc((size_t)(E + N) * 8)};
  size_t rng_o[2]  = {alloc((size_t)(NG + 1) * 4), alloc((size_t)(NG + 1) * 4)};
  size_t dinv_o[2] = {alloc((size_t)N * 4), alloc((size_t)N * 4)};
  size_t invd_o[2] = {alloc((size_t)N * 4), alloc((size_t)N * 4)};
  size_t gid_o[2]  = {alloc((size_t)NG * 2 * 4), alloc((size_t)NG * 2 * 4)};
  size_t qrg_o[2]  = {alloc((size_t)out_size * 16), alloc((size_t)out_size * 16)};
  size_t scr_o[2]  = {alloc((size_t)NG * 2 * 1024 * 4), alloc((size_t)NG * 2 * 1024 * 4)};
  size_t xb_o[2]   = {alloc((size_t)Mpad * 1024 * 2), alloc((size_t)Mpad * 1024 * 2)};
  size_t wt_o[2]   = {alloc((size_t)1024 * 1024 * 2), alloc((size_t)1024 * 1024 * 2)};
  size_t h_o[2]    = {alloc((size_t)Mpad * 1024 * 2), alloc((size_t)Mpad * 1024 * 2)};

  (void)hipMemsetAsync(ws, 0, zero_end, stream);

  for (int br = 0; br < 2; ++br) {
    convert_x_kernel<<<(int)(((long)Mpad * 128 + 255) / 256), 256, 0, stream>>>(
        xs[br], (unsigned short*)(ws + xb_o[br]), N, Mpad);
    wtrans_kernel<<<1024, 256, 0, stream>>>(Ws[br], (unsigned short*)(ws + wt_o[br]));
    deg_kernel<<<(E + 255) / 256, 256, 0, stream>>>(eis[br], (int*)(ws + degi_o[br]), E);
  }
  for (int br = 0; br < 2; ++br) {
    dinv_kernel<<<(N + 255) / 256, 256, 0, stream>>>(
        (int*)(ws + degi_o[br]), (float*)(ws + dinv_o[br]), (float*)(ws + invd_o[br]), N);
  }
  scan2_kernel<<<2, 1024, 0, stream>>>(
      (const int*)(ws + degi_o[0]), (int*)(ws + off_o[0]), (int*)(ws + cur_o[0]),
      (const int*)(ws + degi_o[1]), (int*)(ws + off_o[1]), (int*)(ws + cur_o[1]), N);
  for (int br = 0; br < 2; ++br) {
    fill_kernel<<<(E + N + 255) / 256, 256, 0, stream>>>(
        eis[br], (const float*)(ws + dinv_o[br]), (const float*)(ws + invd_o[br]),
        (int*)(ws + cur_o[br]), (uint2*)(ws + cw_o[br]), E, N);
    ranges_kernel<<<(NG + 256) / 256, 256, 0, stream>>>(
        (const int*)(ws + off_o[br]), (int*)(ws + rng_o[br]), N);
  }
  for (int br = 0; br < 2; ++br) {
    qrange_kernel<<<1, 64, 0, stream>>>(
        bts[br], N, (const int*)(ws + rng_o[br]),
        (int4*)(ws + qrg_o[br]), (int*)(ws + cnt_o[br]), out_size);
  }
  for (int br = 0; br < 2; ++br) {
    dim3 grid(Mpad / BM, 1024 / BN);
    gemm_bf16_kernel<<<grid, 256, 0, stream>>>(
        (const unsigned short*)(ws + xb_o[br]), (const unsigned short*)(ws + wt_o[br]),
        (unsigned short*)(ws + h_o[br]), Mpad, 1024, 1024);
  }
  for (int br = 0; br < 2; ++br) {
    agg_pool_kernel<<<(NG / 4) * NSL, 256, 0, stream>>>(
        (const unsigned short*)(ws + h_o[br]), (const int*)(ws + off_o[br]),
        (const uint2*)(ws + cw_o[br]), bts[br], (const int*)(ws + rng_o[br]),
        bs[br], (float*)(ws + pool_o[br]), (float*)(ws + scr_o[br]), (int*)(ws + gid_o[br]));
  }
  for (int br = 0; br < 2; ++br) {
    pool_reduce_kernel<<<out_size * NSL, 256, 0, stream>>>(
        (const float*)(ws + scr_o[br]), (const int*)(ws + gid_o[br]),
        (const int4*)(ws + qrg_o[br]), (float*)(ws + pool_o[br]));
  }
  fc_final_kernel<<<out_size, 256, 0, stream>>>(
      (const float*)(ws + pool_o[0]), (const float*)(ws + pool_o[1]),
      (const int*)(ws + cnt_o[0]), (const int*)(ws + cnt_o[1]),
      fc1W, fc1b, fc2W, fc2b, finW, finb, out);
}

// Round 6
// 293.180 us; speedup vs baseline: 1.6130x; 1.1824x over previous
//
#include <hip/hip_runtime.h>
#include <stdint.h>

typedef __attribute__((ext_vector_type(8))) short short8;
typedef __attribute__((ext_vector_type(8))) __bf16 bf16x8;
typedef __attribute__((ext_vector_type(4))) float f32x4;

__device__ inline unsigned short f2bf(float f) {
  unsigned u = __float_as_uint(f);
  unsigned r = (u + 0x7FFFu + ((u >> 16) & 1u)) >> 16;  // RNE
  return (unsigned short)r;
}
__device__ inline float bflo(unsigned v) { return __uint_as_float(v << 16); }
__device__ inline float bfhi(unsigned v) { return __uint_as_float(v & 0xFFFF0000u); }
__device__ inline bf16x8 as_bf(short8 v) { return __builtin_bit_cast(bf16x8, v); }

#define GLOAD_LDS16(gp, lp)                                                   \
  __builtin_amdgcn_global_load_lds(                                           \
      (const __attribute__((address_space(1))) void*)(gp),                    \
      (__attribute__((address_space(3))) void*)(lp), 16, 0, 0)

#define NG 2048   // edge-balanced node ranges
#define NSL 8     // dim slices (128 dims = 2.5MB, XCD-L2-resident)

// ---------------- convert X (f32) -> bf16, zero-pad rows >= n; both branches ----------------
__global__ void convert_x_kernel(const float* __restrict__ x0, const float* __restrict__ x1,
                                 unsigned short* __restrict__ xb0, unsigned short* __restrict__ xb1,
                                 int n, int mpad) {
  const float* x = blockIdx.y ? x1 : x0;
  unsigned short* xb = blockIdx.y ? xb1 : xb0;
  long i = (long)blockIdx.x * 256 + threadIdx.x;       // octet index
  long total = (long)mpad * 128;
  if (i >= total) return;
  long e0 = i * 8;
  int row = (int)(e0 >> 10);
  short8 v;
  if (row < n) {
    const float* s = x + e0;
    float4 fa = *(const float4*)(s);
    float4 fb = *(const float4*)(s + 4);
    v[0] = (short)f2bf(fa.x); v[1] = (short)f2bf(fa.y);
    v[2] = (short)f2bf(fa.z); v[3] = (short)f2bf(fa.w);
    v[4] = (short)f2bf(fb.x); v[5] = (short)f2bf(fb.y);
    v[6] = (short)f2bf(fb.z); v[7] = (short)f2bf(fb.w);
  } else {
    v = (short8)0;
  }
  *(short8*)(xb + e0) = v;
}

// ---------------- W (f32, KxN row-major) -> Wt bf16 (NxK row-major); both branches ----------------
__global__ void wtrans_kernel(const float* __restrict__ W0, const float* __restrict__ W1,
                              unsigned short* __restrict__ Wt0, unsigned short* __restrict__ Wt1) {
  const float* W = blockIdx.y ? W1 : W0;
  unsigned short* Wt = blockIdx.y ? Wt1 : Wt0;
  __shared__ float tile[32][33];
  int bx = blockIdx.x & 31;
  int by = blockIdx.x >> 5;
  int tx = threadIdx.x & 31, ty = threadIdx.x >> 5;
#pragma unroll
  for (int r = 0; r < 4; ++r) {
    int k = by * 32 + ty + r * 8;
    tile[ty + r * 8][tx] = W[(long)k * 1024 + bx * 32 + tx];
  }
  __syncthreads();
#pragma unroll
  for (int r = 0; r < 4; ++r) {
    int nrow = bx * 32 + ty + r * 8;
    int kcol = by * 32 + tx;
    Wt[(long)nrow * 1024 + kcol] = f2bf(tile[tx][ty + r * 8]);
  }
}

// ---------------- in-degree; both branches ----------------
__global__ void deg_kernel(const int* __restrict__ ei0, const int* __restrict__ ei1,
                           int* __restrict__ dg0, int* __restrict__ dg1, int E) {
  const int* ei = blockIdx.y ? ei1 : ei0;
  int* degi = blockIdx.y ? dg1 : dg0;
  int e = blockIdx.x * 256 + threadIdx.x;
  if (e >= E) return;
  atomicAdd(&degi[ei[E + e]], 1);
}

// one-pass scan over (deg+1) for both branches; self-loop folded as edge
__global__ __launch_bounds__(1024) void scan2_kernel(
    const int* __restrict__ degA, int* __restrict__ offA, int* __restrict__ curA,
    const int* __restrict__ degB, int* __restrict__ offB, int* __restrict__ curB, int n) {
  const int* deg = blockIdx.x ? degB : degA;
  int* off = blockIdx.x ? offB : offA;
  int* cur = blockIdx.x ? curB : curA;
  __shared__ int wsum[17];
  int t = threadIdx.x, lane = t & 63, w = t >> 6;
  int CH = (n + 1023) >> 10;
  int i0 = t * CH;
  int s = 0;
  for (int i = 0; i < CH; ++i) {
    int idx = i0 + i;
    s += (idx < n) ? (deg[idx] + 1) : 0;
  }
  int inc = s;
  for (int d = 1; d < 64; d <<= 1) {
    int x = __shfl_up(inc, d);
    if (lane >= d) inc += x;
  }
  if (lane == 63) wsum[w] = inc;
  __syncthreads();
  if (t == 0) {
    int r = 0;
    for (int k = 0; k < 16; ++k) { int x = wsum[k]; wsum[k] = r; r += x; }
    wsum[16] = r;
  }
  __syncthreads();
  int run = wsum[w] + inc - s;
  for (int i = 0; i < CH; ++i) {
    int idx = i0 + i;
    if (idx < n) {
      off[idx] = run;
      cur[idx] = run;
      run += deg[idx] + 1;
    }
  }
  if (t == 0) off[n] = wsum[16];
}

// CSR fill with packed {src, weight}; weight from deg via rsqrt; e >= E are self-loops
__global__ void fill_kernel(const int* __restrict__ ei0, const int* __restrict__ ei1,
                            const int* __restrict__ dg0, const int* __restrict__ dg1,
                            int* __restrict__ cur0, int* __restrict__ cur1,
                            uint2* __restrict__ cw0, uint2* __restrict__ cw1, int E, int N) {
  int br = blockIdx.y;
  const int* ei = br ? ei1 : ei0;
  const int* dg = br ? dg1 : dg0;
  int* cur = br ? cur1 : cur0;
  uint2* cw = br ? cw1 : cw0;
  int e = blockIdx.x * 256 + threadIdx.x;
  if (e >= E + N) return;
  int s, d; float w;
  if (e < E) {
    s = ei[e]; d = ei[E + e];
    w = rsqrtf((float)(dg[s] + 1)) * rsqrtf((float)(dg[d] + 1));
  } else {
    s = e - E; d = s;
    w = 1.0f / (float)(dg[s] + 1);
  }
  int p = atomicAdd(&cur[d], 1);
  uint2 v; v.x = (unsigned)s; v.y = __float_as_uint(w);
  cw[p] = v;
}

// edge-balanced node ranges; both branches
__global__ void ranges_kernel(const int* __restrict__ off0, const int* __restrict__ off1,
                              int* __restrict__ rng0, int* __restrict__ rng1, int n) {
  const int* off = blockIdx.y ? off1 : off0;
  int* rng = blockIdx.y ? rng1 : rng0;
  int q = blockIdx.x * 256 + threadIdx.x;
  if (q > NG) return;
  if (q == NG) { rng[q] = n; return; }
  long Etot = off[n];
  long target = (long)q * Etot;
  int lo = 0, hi = n;
  while (lo < hi) {
    int mid = (lo + hi) >> 1;
    if ((long)off[mid] * NG >= target) hi = mid; else lo = mid + 1;
  }
  rng[q] = lo;
}

// per-graph spans (binary search on sorted batch, no atomics), counts, q-window; both branches
__global__ void qrange_kernel(const int* __restrict__ b0, const int* __restrict__ b1, int N,
                              const int* __restrict__ rng0, const int* __restrict__ rng1,
                              int4* __restrict__ qrg0, int4* __restrict__ qrg1,
                              int* __restrict__ cnt0, int* __restrict__ cnt1, int nb_) {
  int t = threadIdx.x;
  int g = t & 63, br = t >> 6;
  if (g >= nb_ || br > 1) return;
  const int* batch = br ? b1 : b0;
  const int* rng = br ? rng1 : rng0;
  int4* qrg = br ? qrg1 : qrg0;
  int* cnt = br ? cnt1 : cnt0;
  int lo = 0, hi = N;
  while (lo < hi) { int m = (lo + hi) >> 1; if (batch[m] < g) lo = m + 1; else hi = m; }
  int gs = lo;
  lo = 0; hi = N;
  while (lo < hi) { int m = (lo + hi) >> 1; if (batch[m] <= g) lo = m + 1; else hi = m; }
  int ge = lo;
  cnt[g] = ge - gs;
  lo = 0; hi = NG - 1;
  while (lo < hi) { int m = (lo + hi) >> 1; if (rng[m + 1] > gs) hi = m; else lo = m + 1; }
  int qlo = lo;
  lo = 0; hi = NG - 1;
  while (lo < hi) { int m = (lo + hi + 1) >> 1; if (rng[m] < ge) lo = m; else hi = m - 1; }
  int4 r; r.x = qlo; r.y = lo; r.z = gs; r.w = ge;
  qrg[g] = r;
}

// ---------------- GEMM: C[M,N] = A[M,K] @ Bt[N,K]^T; both branches via blockIdx.z ----------------
#define BM 128
#define BN 128
#define BK 32

__global__ __launch_bounds__(256) void gemm_bf16_kernel(
    const unsigned short* __restrict__ A0, const unsigned short* __restrict__ A1,
    const unsigned short* __restrict__ B0, const unsigned short* __restrict__ B1,
    unsigned short* __restrict__ C0, unsigned short* __restrict__ C1,
    int M, int Nn, int K) {
  const unsigned short* A = blockIdx.z ? A1 : A0;
  const unsigned short* Bt = blockIdx.z ? B1 : B0;
  unsigned short* C = blockIdx.z ? C1 : C0;
  __shared__ alignas(16) unsigned short As[BM * BK];
  __shared__ alignas(16) unsigned short Bs[BN * BK];
  int t = threadIdx.x;
  int lane = t & 63;
  int w = t >> 6;
  int wm = (w >> 1) * 64, wn = (w & 1) * 64;
  long m0 = (long)blockIdx.x * BM;
  long n0 = (long)blockIdx.y * BN;
  int srow = t >> 2;
  int scol = (t & 3) * 8;
  const unsigned short* Ag = A + (m0 + srow) * K + scol;
  const unsigned short* Bg = Bt + (n0 + srow) * K + scol;
  unsigned short* AsP = As + t * 8;
  unsigned short* BsP = Bs + t * 8;
  int fr = lane & 15;
  int fk = (lane >> 4) * 8;
  const unsigned short* afp = As + (wm + fr) * BK + fk;
  const unsigned short* bfp = Bs + (wn + fr) * BK + fk;
  f32x4 acc[4][4] = {};
  for (int k0 = 0; k0 < K; k0 += BK) {
    __syncthreads();
    GLOAD_LDS16(Ag + k0, AsP);
    GLOAD_LDS16(Ag + (long)64 * K + k0, AsP + 2048);
    GLOAD_LDS16(Bg + k0, BsP);
    GLOAD_LDS16(Bg + (long)64 * K + k0, BsP + 2048);
    __syncthreads();
    short8 af[4], bf[4];
#pragma unroll
    for (int i = 0; i < 4; ++i)
      af[i] = *(const short8*)(afp + i * 16 * BK);
#pragma unroll
    for (int i = 0; i < 4; ++i)
      bf[i] = *(const short8*)(bfp + i * 16 * BK);
#pragma unroll
    for (int i = 0; i < 4; ++i)
#pragma unroll
      for (int j = 0; j < 4; ++j)
        acc[i][j] = __builtin_amdgcn_mfma_f32_16x16x32_bf16(as_bf(af[i]), as_bf(bf[j]),
                                                            acc[i][j], 0, 0, 0);
  }
  int cr = (lane >> 4) * 4;
  int cc = lane & 15;
#pragma unroll
  for (int i = 0; i < 4; ++i)
#pragma unroll
    for (int j = 0; j < 4; ++j) {
      long row = m0 + wm + i * 16 + cr;
      long col = n0 + wn + j * 16 + cc;
      unsigned short* cp = C + row * Nn + col;
#pragma unroll
      for (int r = 0; r < 4; ++r)
        cp[(long)r * Nn] = f2bf(acc[i][j][r]);
    }
}

// ---------------- fused aggregate + bias + leaky + partial-pool (atomic-free) ----------------
// One 64-lane wave per (q, slice); 4 quarter-waves process edges e..e+3 of the SAME node
// (uniform, zero-weight padded). Lane loads uint4 = 8 dims; 16 lanes x 8 = 128-dim slice
// (2.5MB, XCD-L2-resident via slice = blockIdx.x & 7). Cross-quarter reduce: shfl_xor 16,32.
// Range-boundary partials go non-atomically to scratch[q][slot][1024]; interior graphs (rare)
// use atomics. Both branches via blockIdx.y.
__global__ __launch_bounds__(256) void agg_pool_kernel(
    const unsigned short* __restrict__ H0, const unsigned short* __restrict__ H1,
    const int* __restrict__ off0, const int* __restrict__ off1,
    const uint2* __restrict__ cw0, const uint2* __restrict__ cw1,
    const int* __restrict__ b0, const int* __restrict__ b1,
    const int* __restrict__ rng0, const int* __restrict__ rng1,
    const float* __restrict__ bias0, const float* __restrict__ bias1,
    float* __restrict__ pool0, float* __restrict__ pool1,
    float* __restrict__ scr0, float* __restrict__ scr1,
    int* __restrict__ gid0, int* __restrict__ gid1) {
  int br = blockIdx.y;
  const unsigned short* H = br ? H1 : H0;
  const int* off = br ? off1 : off0;
  const uint2* cw = br ? cw1 : cw0;
  const int* batch = br ? b1 : b0;
  const int* rng = br ? rng1 : rng0;
  const float* bias = br ? bias1 : bias0;
  float* pool = br ? pool1 : pool0;
  float* scratch = br ? scr1 : scr0;
  int* gid = br ? gid1 : gid0;

  int t = threadIdx.x;
  int wv = t >> 6, lane = t & 63, qw = lane >> 4, l16 = lane & 15;
  int slice = blockIdx.x & 7;
  int part = blockIdx.x >> 3;
  int q = part * 4 + wv;
  int d0 = slice * 128 + l16 * 8;
  int na = rng[q], nb = rng[q + 1];
  int g0 = -1, g1 = -1;
  if (na < nb) {
    float4 bv0 = *(const float4*)(bias + d0);
    float4 bv1 = *(const float4*)(bias + d0 + 4);
    float bv[8] = {bv0.x, bv0.y, bv0.z, bv0.w, bv1.x, bv1.y, bv1.z, bv1.w};
    float pacc[8] = {};
    int curg = batch[na];
    int fi = 0;
    for (int nd = na; nd < nb; ++nd) {
      int g = batch[nd];
      if (g != curg) {
        if (fi == 0) {
          g0 = curg;
          if (qw == 0) {
            float* sp = scratch + ((long)q * 2 + 0) * 1024 + d0;
            *(float4*)sp = make_float4(pacc[0], pacc[1], pacc[2], pacc[3]);
            *(float4*)(sp + 4) = make_float4(pacc[4], pacc[5], pacc[6], pacc[7]);
          }
        } else {
          if (qw == 0) {
            float* pp = pool + (long)curg * 1024 + d0;
#pragma unroll
            for (int k = 0; k < 8; ++k) atomicAdd(pp + k, pacc[k]);
          }
        }
        ++fi;
#pragma unroll
        for (int k = 0; k < 8; ++k) pacc[k] = 0.f;
        curg = g;
      }
      float a[8] = {};
      int eb = off[nd], ee = off[nd + 1];
      for (int e = eb; e < ee; e += 4) {
        int ei = e + qw;
        int ec = ei < ee ? ei : ee - 1;
        uint2 c = cw[ec];
        float ww = ei < ee ? __uint_as_float(c.y) : 0.f;
        uint4 hv = *(const uint4*)(H + (long)c.x * 1024 + d0);
        a[0] += ww * bflo(hv.x); a[1] += ww * bfhi(hv.x);
        a[2] += ww * bflo(hv.y); a[3] += ww * bfhi(hv.y);
        a[4] += ww * bflo(hv.z); a[5] += ww * bfhi(hv.z);
        a[6] += ww * bflo(hv.w); a[7] += ww * bfhi(hv.w);
      }
#pragma unroll
      for (int k = 0; k < 8; ++k) {
        float v = a[k];
        v += __shfl_xor(v, 16);
        v += __shfl_xor(v, 32);
        v += bv[k];
        pacc[k] += (v >= 0.f) ? v : 0.01f * v;
      }
    }
    if (fi == 0) {
      g0 = curg;
      if (qw == 0) {
        float* sp = scratch + ((long)q * 2 + 0) * 1024 + d0;
        *(float4*)sp = make_float4(pacc[0], pacc[1], pacc[2], pacc[3]);
        *(float4*)(sp + 4) = make_float4(pacc[4], pacc[5], pacc[6], pacc[7]);
      }
    } else {
      g1 = curg;
      if (qw == 0) {
        float* sp = scratch + ((long)q * 2 + 1) * 1024 + d0;
        *(float4*)sp = make_float4(pacc[0], pacc[1], pacc[2], pacc[3]);
        *(float4*)(sp + 4) = make_float4(pacc[4], pacc[5], pacc[6], pacc[7]);
      }
    }
  }
  if (slice == 0 && lane == 0) {
    gid[q * 2] = g0;
    gid[q * 2 + 1] = g1;
  }
}

// sum scratch partials into pool; both branches
__global__ __launch_bounds__(256) void pool_reduce_kernel(
    const float* __restrict__ scr0, const float* __restrict__ scr1,
    const int* __restrict__ gid0, const int* __restrict__ gid1,
    const int4* __restrict__ qrg0, const int4* __restrict__ qrg1,
    float* __restrict__ pool0, float* __restrict__ pool1) {
  int br = blockIdx.y;
  const float* scratch = br ? scr1 : scr0;
  const int* gid = br ? gid1 : gid0;
  const int4* qrg = br ? qrg1 : qrg0;
  float* pool = br ? pool1 : pool0;
  int g = blockIdx.x >> 2;
  int slice = blockIdx.x & 3;
  int tid = threadIdx.x;
  int4 r = qrg[g];
  float s = 0.f;
  for (int q = r.x; q <= r.y; ++q) {
    int a = gid[q * 2], b = gid[q * 2 + 1];
    if (a == g) s += scratch[((long)q * 2 + 0) * 1024 + slice * 256 + tid];
    if (b == g) s += scratch[((long)q * 2 + 1) * 1024 + slice * 256 + tid];
  }
  long idx = (long)g * 1024 + slice * 256 + tid;
  pool[idx] += s;
}

// ---------------- final: mean-pool finalize + fc1/fc2 + leaky + concat @ final_W ----------------
__global__ __launch_bounds__(256) void fc_final_kernel(
    const float* __restrict__ pool1, const float* __restrict__ pool2,
    const int* __restrict__ cnt1, const int* __restrict__ cnt2,
    const float* __restrict__ fc1W, const float* __restrict__ fc1b,
    const float* __restrict__ fc2W, const float* __restrict__ fc2b,
    const float* __restrict__ finW, const float* __restrict__ finb,
    float* __restrict__ out) {
  __shared__ float p1[1024], p2[1024];
  __shared__ float red[256];
  int g = blockIdx.x, t = threadIdx.x;
  float ic1 = 1.0f / (float)max(cnt1[g], 1);
  float ic2 = 1.0f / (float)max(cnt2[g], 1);
  for (int i = t; i < 1024; i += 256) {
    p1[i] = pool1[(long)g * 1024 + i] * ic1;
    p2[i] = pool2[(long)g * 1024 + i] * ic2;
  }
  __syncthreads();
  float contrib;
  if (t < 128) {
    float a = 0.f;
    for (int k = 0; k < 1024; ++k) a += p1[k] * fc1W[(long)k * 128 + t];
    a += fc1b[t];
    a = a >= 0.f ? a : 0.01f * a;
    contrib = a * finW[t];
  } else {
    int j = t - 128;
    float a = 0.f;
    for (int k = 0; k < 1024; ++k) a += p2[k] * fc2W[(long)k * 128 + j];
    a += fc2b[j];
    a = a >= 0.f ? a : 0.01f * a;
    contrib = a * finW[128 + j];
  }
  red[t] = contrib;
  __syncthreads();
  for (int s = 128; s; s >>= 1) {
    if (t < s) red[t] += red[t + s];
    __syncthreads();
  }
  if (t == 0) out[g] = red[0] + finb[0];
}

extern "C" void kernel_launch(void* const* d_in, const int* in_sizes, int n_in,
                              void* d_out, int out_size, void* d_ws, size_t ws_size,
                              hipStream_t stream) {
  (void)n_in; (void)ws_size;
  const float* xs[2]   = {(const float*)d_in[0], (const float*)d_in[3]};
  const int* eis[2]    = {(const int*)d_in[1], (const int*)d_in[4]};
  const int* bts[2]    = {(const int*)d_in[2], (const int*)d_in[5]};
  const float* Ws[2]   = {(const float*)d_in[6], (const float*)d_in[10]};
  const float* bs[2]   = {(const float*)d_in[7], (const float*)d_in[11]};
  const float* fc1W = (const float*)d_in[8];
  const float* fc1b = (const float*)d_in[9];
  const float* fc2W = (const float*)d_in[12];
  const float* fc2b = (const float*)d_in[13];
  const float* finW = (const float*)d_in[14];
  const float* finb = (const float*)d_in[15];
  float* out = (float*)d_out;

  const int N = in_sizes[2];
  const int E = in_sizes[1] / 2;
  const int Mpad = ((N + 127) / 128) * 128;

  uint8_t* ws = (uint8_t*)d_ws;
  size_t o = 0;
  auto alloc = [&](size_t bytes) { size_t r = o; o += (bytes + 255) & ~(size_t)255; return r; };
  size_t degi_o[2] = {alloc((size_t)N * 4), alloc((size_t)N * 4)};
  size_t pool_o[2] = {alloc((size_t)out_size * 1024 * 4), alloc((size_t)out_size * 1024 * 4)};
  size_t zero_end = o;
  size_t cnt_o[2]  = {alloc((size_t)out_size * 4), alloc((size_t)out_size * 4)};
  size_t cur_o[2]  = {alloc((size_t)N * 4), alloc((size_t)N * 4)};
  size_t off_o[2]  = {alloc((size_t)(N + 1) * 4), alloc((size_t)(N + 1) * 4)};
  size_t cw_o[2]   = {alloc((size_t)(E + N) * 8), alloc((size_t)(E + N) * 8)};
  size_t rng_o[2]  = {alloc((size_t)(NG + 1) * 4), alloc((size_t)(NG + 1) * 4)};
  size_t gid_o[2]  = {alloc((size_t)NG * 2 * 4), alloc((size_t)NG * 2 * 4)};
  size_t qrg_o[2]  = {alloc((size_t)out_size * 16), alloc((size_t)out_size * 16)};
  size_t scr_o[2]  = {alloc((size_t)NG * 2 * 1024 * 4), alloc((size_t)NG * 2 * 1024 * 4)};
  size_t xb_o[2]   = {alloc((size_t)Mpad * 1024 * 2), alloc((size_t)Mpad * 1024 * 2)};
  size_t wt_o[2]   = {alloc((size_t)1024 * 1024 * 2), alloc((size_t)1024 * 1024 * 2)};
  size_t h_o[2]    = {alloc((size_t)Mpad * 1024 * 2), alloc((size_t)Mpad * 1024 * 2)};

  (void)hipMemsetAsync(ws, 0, zero_end, stream);

  {
    dim3 g((unsigned)(((long)Mpad * 128 + 255) / 256), 2);
    convert_x_kernel<<<g, 256, 0, stream>>>(
        xs[0], xs[1], (unsigned short*)(ws + xb_o[0]), (unsigned short*)(ws + xb_o[1]), N, Mpad);
  }
  wtrans_kernel<<<dim3(1024, 2), 256, 0, stream>>>(
      Ws[0], Ws[1], (unsigned short*)(ws + wt_o[0]), (unsigned short*)(ws + wt_o[1]));
  deg_kernel<<<dim3((E + 255) / 256, 2), 256, 0, stream>>>(
      eis[0], eis[1], (int*)(ws + degi_o[0]), (int*)(ws + degi_o[1]), E);
  scan2_kernel<<<2, 1024, 0, stream>>>(
      (const int*)(ws + degi_o[0]), (int*)(ws + off_o[0]), (int*)(ws + cur_o[0]),
      (const int*)(ws + degi_o[1]), (int*)(ws + off_o[1]), (int*)(ws + cur_o[1]), N);
  fill_kernel<<<dim3((E + N + 255) / 256, 2), 256, 0, stream>>>(
      eis[0], eis[1], (const int*)(ws + degi_o[0]), (const int*)(ws + degi_o[1]),
      (int*)(ws + cur_o[0]), (int*)(ws + cur_o[1]),
      (uint2*)(ws + cw_o[0]), (uint2*)(ws + cw_o[1]), E, N);
  ranges_kernel<<<dim3((NG + 256) / 256, 2), 256, 0, stream>>>(
      (const int*)(ws + off_o[0]), (const int*)(ws + off_o[1]),
      (int*)(ws + rng_o[0]), (int*)(ws + rng_o[1]), N);
  qrange_kernel<<<1, 128, 0, stream>>>(
      bts[0], bts[1], N, (const int*)(ws + rng_o[0]), (const int*)(ws + rng_o[1]),
      (int4*)(ws + qrg_o[0]), (int4*)(ws + qrg_o[1]),
      (int*)(ws + cnt_o[0]), (int*)(ws + cnt_o[1]), out_size);
  gemm_bf16_kernel<<<dim3(Mpad / BM, 1024 / BN, 2), 256, 0, stream>>>(
      (const unsigned short*)(ws + xb_o[0]), (const unsigned short*)(ws + xb_o[1]),
      (const unsigned short*)(ws + wt_o[0]), (const unsigned short*)(ws + wt_o[1]),
      (unsigned short*)(ws + h_o[0]), (unsigned short*)(ws + h_o[1]), Mpad, 1024, 1024);
  agg_pool_kernel<<<dim3((NG / 4) * NSL, 2), 256, 0, stream>>>(
      (const unsigned short*)(ws + h_o[0]), (const unsigned short*)(ws + h_o[1]),
      (const int*)(ws + off_o[0]), (const int*)(ws + off_o[1]),
      (const uint2*)(ws + cw_o[0]), (const uint2*)(ws + cw_o[1]),
      bts[0], bts[1],
      (const int*)(ws + rng_o[0]), (const int*)(ws + rng_o[1]),
      bs[0], bs[1],
      (float*)(ws + pool_o[0]), (float*)(ws + pool_o[1]),
      (float*)(ws + scr_o[0]), (float*)(ws + scr_o[1]),
      (int*)(ws + gid_o[0]), (int*)(ws + gid_o[1]));
  pool_reduce_kernel<<<dim3(out_size * 4, 2), 256, 0, stream>>>(
      (const float*)(ws + scr_o[0]), (const float*)(ws + scr_o[1]),
      (const int*)(ws + gid_o[0]), (const int*)(ws + gid_o[1]),
      (const int4*)(ws + qrg_o[0]), (const int4*)(ws + qrg_o[1]),
      (float*)(ws + pool_o[0]), (float*)(ws + pool_o[1]));
  fc_final_kernel<<<out_size, 256, 0, stream>>>(
      (const float*)(ws + pool_o[0]), (const float*)(ws + pool_o[1]),
      (const int*)(ws + cnt_o[0]), (const int*)(ws + cnt_o[1]),
      fc1W, fc1b, fc2W, fc2b, finW, finb, out);
}